// Round 5
// baseline (237.162 us; speedup 1.0000x reference)
//
#include <hip/hip_runtime.h>

#define B_  8
#define C_  128
#define H_  96
#define W_  160
#define HWp (H_ * W_)   // 15360 = one channel plane
#define PADY 4
#define HP  104         // H_ + 2*PADY
#define WP  176         // W_ + 16: halo (+8) plus slack so the 32-wide DMA window never goes OOB

typedef short  short8  __attribute__((ext_vector_type(8)));
typedef float  floatx4 __attribute__((ext_vector_type(4)));

// round-to-nearest-even fp32 -> bf16, packed pair (a low 16, b high 16)
__device__ __forceinline__ unsigned pk_bf16(float a, float b) {
    unsigned ua = __float_as_uint(a);
    unsigned ub = __float_as_uint(b);
    ua = (ua + 0x7FFFu + ((ua >> 16) & 1u)) >> 16;
    ub = (ub + 0x7FFFu + ((ub >> 16) & 1u)) & 0xFFFF0000u;
    return ua | ub;
}

// async 16B-per-lane global->LDS DMA (offset arg must be a literal constant,
// so chunk offsets are folded into the global pointer at the call site).
__device__ __forceinline__ void gload_lds16(const void* g, void* l) {
    __builtin_amdgcn_global_load_lds(
        (const __attribute__((address_space(1))) unsigned int*)g,
        (__attribute__((address_space(3))) unsigned int*)l, 16, 0, 0);
}

// ---------------------------------------------------------------------------
// Prep v3: fp32 NCHW -> bf16 NHWC, streaming transpose.
// Key: flatten H*W. A block owns 640 CONSECUTIVE positions (4 rows) of one
// batch; thread t = position g*640+t. At channel step j all 10 waves read
// 2560 contiguous bytes of plane j (1 instruction = 1 contiguous 256B
// segment; pages hit back-to-back), then advance to the next plane. Packs
// c-pairs in-register, stores 16B NHWC records (L2 write-combines -> full
// lines; verified ideal WRITE_SIZE in round 4). Zero LDS, zero barriers.
//   id <192  : two interior rows -> two_t (shifted +4,+4)
//   id <384  : one -> one_t
//   id >=384 : zero two_t halo (border rows + x-halo/slack columns)
// ---------------------------------------------------------------------------
__global__ __launch_bounds__(640, 1)
void prep_kernel(const float* __restrict__ two, const float* __restrict__ one,
                 unsigned short* __restrict__ two_t,
                 unsigned short* __restrict__ one_t) {
    const int id  = blockIdx.x;
    const int tid = threadIdx.x;

    if (id < 192) {
        // ----- two interior: (b, 4-row group) -----
        const int b = id & 7;
        const int g = id >> 3;                 // 0..23
        const int p = g * 640 + tid;           // 0..15359
        const int y = p / 160;                 // const-div -> magic mul
        const int x = p - y * 160;
        const float* src = two + (size_t)(b * C_) * HWp + p;
        unsigned short* d = two_t + ((size_t)((b * HP + y + PADY) * WP) + (x + 4)) * C_;
        #pragma unroll
        for (int cg = 0; cg < 16; ++cg) {
            float v[8];
            #pragma unroll
            for (int k = 0; k < 8; ++k) v[k] = src[(size_t)(cg * 8 + k) * HWp];
            uint4 u;
            u.x = pk_bf16(v[0], v[1]);
            u.y = pk_bf16(v[2], v[3]);
            u.z = pk_bf16(v[4], v[5]);
            u.w = pk_bf16(v[6], v[7]);
            *reinterpret_cast<uint4*>(d + cg * 8) = u;
        }
    } else if (id < 384) {
        // ----- one: (b, 4-row group) -----
        const int id2 = id - 192;
        const int b = id2 & 7;
        const int g = id2 >> 3;                // 0..23
        const int p = g * 640 + tid;
        const float* src = one + (size_t)(b * C_) * HWp + p;
        unsigned short* d = one_t + ((size_t)b * HWp + p) * C_;
        #pragma unroll
        for (int cg = 0; cg < 16; ++cg) {
            float v[8];
            #pragma unroll
            for (int k = 0; k < 8; ++k) v[k] = src[(size_t)(cg * 8 + k) * HWp];
            uint4 u;
            u.x = pk_bf16(v[0], v[1]);
            u.y = pk_bf16(v[2], v[3]);
            u.z = pk_bf16(v[4], v[5]);
            u.w = pk_bf16(v[6], v[7]);
            *reinterpret_cast<uint4*>(d + cg * 8) = u;
        }
    } else {
        // ----- two_t halo zero: 23552 positions (8 border rows * 176 +
        //       96 interior rows * 16 halo/slack cols, x 8 batches) -----
        const int idx = (id - 384) * 640 + tid;
        if (idx < 23552) {
            const int b = idx / 2944;
            const int r = idx - b * 2944;
            int ypad, xp;
            if (r < 1408) {                    // full border rows 0..3, 100..103
                const int rb = r / 176;
                ypad = (rb < 4) ? rb : 96 + rb;
                xp   = r - rb * 176;
            } else {                           // interior rows: cols 0..3, 164..175
                const int rr = r - 1408;
                ypad = PADY + (rr >> 4);
                const int k = rr & 15;
                xp   = (k < 4) ? k : 160 + k;
            }
            unsigned short* d = two_t + ((size_t)(b * HP + ypad) * WP + xp) * C_;
            const uint4 z{0u, 0u, 0u, 0u};
            #pragma unroll
            for (int r2 = 0; r2 < 16; ++r2)
                *reinterpret_cast<uint4*>(d + r2 * 8) = z;
        }
    }
}

// ---------------------------------------------------------------------------
// Pass 2: band-GEMM correlation, pure-DMA staging (both operands via
// global_load_lds from bf16 NHWC), counted vmcnt, raw barriers, coalesced
// LDS-staged epilogue. (unchanged — harness-verified, ~29 µs)
// ---------------------------------------------------------------------------
__global__ __launch_bounds__(512, 4)
void corr2_kernel(const unsigned short* __restrict__ one_t,
                  const unsigned short* __restrict__ two_t,
                  float* __restrict__ out) {
    __shared__ uint4 two_q[2][16 * 128];   // 32 KB x2: [ry16][ct2*64 + kg4*16 + n16]
    __shared__ uint4 one_q[2][8 * 64];     //  8 KB x2: [y8][kg4*16 + x16]  -> 80 KB total

    const int id = blockIdx.x;
    const int b  = id & 7;            // one batch per XCD
    const int jj = id >> 3;           // 0..119
    const int yt = jj % 12;
    const int xt = jj / 12;
    const int y0 = yt * 8;
    const int x0 = xt * 16;

    const int tid  = threadIdx.x;
    const int lane = tid & 63;
    const int w    = tid >> 6;        // wave id = y-row within tile
    const int kq   = lane >> 4;       // 0..3
    const int nn   = lane & 15;

    // ---- DMA source pointers (per-lane) ----
    const unsigned short* p_one =
        one_t + ((size_t)((b * H_ + y0 + w) * W_ + x0 + nn)) * C_ + kq * 8;
    const unsigned short* p_two[4];
    #pragma unroll
    for (int q = 0; q < 4; ++q) {
        const int ii = w * 4 + q;
        const int ry = ii >> 1, ct = ii & 1;
        p_two[q] = two_t + ((size_t)((b * HP + y0 + ry) * WP + x0 + ct * 16 + nn)) * C_ + kq * 8;
    }

    #define ISSUE(ck, buf) do {                                                  \
        gload_lds16(p_one + (ck) * 32, &one_q[buf][w * 64]);                     \
        _Pragma("unroll")                                                        \
        for (int q = 0; q < 4; ++q)                                              \
            gload_lds16(p_two[q] + (ck) * 32, &two_q[buf][(w * 4 + q) * 64]);    \
    } while (0)

    // raw barrier: drain own LDS ops, do NOT drain vmcnt (DMA stays in flight)
    #define BAR() asm volatile("s_waitcnt lgkmcnt(0)\n\ts_barrier" ::: "memory")

    floatx4 acc[9][2];
    #pragma unroll
    for (int dy = 0; dy < 9; ++dy) {
        acc[dy][0] = floatx4{0.f, 0.f, 0.f, 0.f};
        acc[dy][1] = floatx4{0.f, 0.f, 0.f, 0.f};
    }

    // ---- prologue: 2 chunks in flight (5 vmem ops each) ----
    ISSUE(0, 0);
    ISSUE(1, 1);

    #pragma unroll
    for (int ck = 0; ck < 4; ++ck) {
        const int cur = ck & 1;
        if (ck < 3) asm volatile("s_waitcnt vmcnt(5)" ::: "memory");
        else        asm volatile("s_waitcnt vmcnt(0)" ::: "memory");
        BAR();   // all waves' DMAs for chunk ck have landed -> safe to read

        const short8 A = *reinterpret_cast<const short8*>(&one_q[cur][w * 64 + lane]);
        #pragma unroll
        for (int dy = 0; dy < 9; ++dy) {
            const int ry = w + dy;
            const short8 Bt0 = *reinterpret_cast<const short8*>(&two_q[cur][ry * 128 + lane]);
            const short8 Bt1 = *reinterpret_cast<const short8*>(&two_q[cur][ry * 128 + 64 + lane]);
            acc[dy][0] = __builtin_amdgcn_mfma_f32_16x16x32_bf16(A, Bt0, acc[dy][0], 0, 0, 0);
            acc[dy][1] = __builtin_amdgcn_mfma_f32_16x16x32_bf16(A, Bt1, acc[dy][1], 0, 0, 0);
        }
        BAR();   // all reads of buf[cur] complete before anyone refills it

        if (ck < 2) ISSUE(ck + 2, cur);
    }

    // ---- epilogue: stage into LDS (overlaid on dead two_q), store coalesced ----
    __syncthreads();                               // everyone done with two_q
    float* ep = reinterpret_cast<float*>(&two_q[0][0]);   // 81*130*4 = 42 KB < 64 KB
    const float scale = 1.0f / (float)C_;
    #pragma unroll
    for (int dy = 0; dy < 9; ++dy) {
        #pragma unroll
        for (int ct = 0; ct < 2; ++ct) {
            floatx4 v = acc[dy][ct];
            #pragma unroll
            for (int r = 0; r < 4; ++r) {
                const int m  = kq * 4 + r;
                const int dx = nn - m + ct * 16;
                if ((unsigned)dx <= 8u)
                    ep[(dy * 9 + dx) * 130 + w * 16 + m] = v[r] * scale;
            }
        }
    }
    __syncthreads();
    // 81 planes * 128 floats = 10368 dwords; lanes cover x fastest -> full 64B lines
    #pragma unroll
    for (int i = 0; i < 21; ++i) {
        const int g = tid + i * 512;
        if (g < 81 * 128) {
            const int p   = g >> 7;
            const int loc = g & 127;               // yy*16 + xx
            const int yy  = loc >> 4, xx = loc & 15;
            out[((size_t)(b * 81 + p) * H_ + y0 + yy) * W_ + x0 + xx] = ep[p * 130 + loc];
        }
    }
    #undef ISSUE
    #undef BAR
}

// ---------------------------------------------------------------------------
// Fallback: harness-verified single-pass kernel (used if workspace too small)
// ---------------------------------------------------------------------------
__global__ __launch_bounds__(512, 2)
void corr_kernel(const float* __restrict__ one, const float* __restrict__ two,
                 float* __restrict__ out) {
    __shared__ uint4 one_q[2][8 * 64];
    __shared__ uint4 two_q[2][16 * 128];

    const int id = blockIdx.x;
    const int b  = id & 7;
    const int jj = id >> 3;
    const int yt = jj % 12;
    const int xt = jj / 12;
    const int y0 = yt * 8;
    const int x0 = xt * 16;

    const int tid  = threadIdx.x;
    const int lane = tid & 63;
    const int w    = tid >> 6;

    const int o_xl  = tid & 15;
    const int o_yl  = (tid >> 4) & 7;
    const int o_kg  = tid >> 7;
    const int o_rec = o_yl * 64 + o_kg * 16 + o_xl;

    const int t_cx  = tid & 31;
    const int t_ry  = tid >> 5;
    const int t_y   = y0 - 4 + t_ry;
    const int t_gx  = x0 - 4 + t_cx;
    const bool t_valid = ((unsigned)t_y < H_) && ((unsigned)t_gx < W_) && (t_cx < 24);
    const int t_rec = t_ry * 128 + (t_cx >> 4) * 64 + (t_cx & 15);

    const float* o_base = one + ((size_t)(b * C_ + 8 * o_kg) * H_ + (y0 + o_yl)) * W_ + (x0 + o_xl);
    const float* t_base = two + ((size_t)(b * C_) * H_ + t_y) * W_ + t_gx;

    float ro[8];
    float rt[32];

    floatx4 acc[9][2];
    #pragma unroll
    for (int dy = 0; dy < 9; ++dy) {
        acc[dy][0] = floatx4{0.f, 0.f, 0.f, 0.f};
        acc[dy][1] = floatx4{0.f, 0.f, 0.f, 0.f};
    }

    {
        const float* p1 = o_base;
        #pragma unroll
        for (int i = 0; i < 8; ++i) ro[i] = p1[(size_t)i * HWp];
        if (t_valid) {
            const float* p2 = t_base;
            #pragma unroll
            for (int i = 0; i < 32; ++i) rt[i] = p2[(size_t)i * HWp];
        } else {
            #pragma unroll
            for (int i = 0; i < 32; ++i) rt[i] = 0.f;
        }
    }

    #pragma unroll
    for (int ck = 0; ck < 4; ++ck) {
        const int bf = ck & 1;
        {
            uint4 v;
            v.x = pk_bf16(ro[0], ro[1]);
            v.y = pk_bf16(ro[2], ro[3]);
            v.z = pk_bf16(ro[4], ro[5]);
            v.w = pk_bf16(ro[6], ro[7]);
            one_q[bf][o_rec] = v;
            #pragma unroll
            for (int kg = 0; kg < 4; ++kg) {
                uint4 u;
                u.x = pk_bf16(rt[kg * 8 + 0], rt[kg * 8 + 1]);
                u.y = pk_bf16(rt[kg * 8 + 2], rt[kg * 8 + 3]);
                u.z = pk_bf16(rt[kg * 8 + 4], rt[kg * 8 + 5]);
                u.w = pk_bf16(rt[kg * 8 + 6], rt[kg * 8 + 7]);
                two_q[bf][t_rec + kg * 16] = u;
            }
        }
        __syncthreads();

        if (ck < 3) {
            const float* p1 = o_base + (size_t)((ck + 1) * 32) * HWp;
            #pragma unroll
            for (int i = 0; i < 8; ++i) ro[i] = p1[(size_t)i * HWp];
            if (t_valid) {
                const float* p2 = t_base + (size_t)((ck + 1) * 32) * HWp;
                #pragma unroll
                for (int i = 0; i < 32; ++i) rt[i] = p2[(size_t)i * HWp];
            }
        }

        const short8 A = *reinterpret_cast<const short8*>(&one_q[bf][w * 64 + lane]);
        #pragma unroll
        for (int dy = 0; dy < 9; ++dy) {
            const int ry = w + dy;
            const short8 Bt0 = *reinterpret_cast<const short8*>(&two_q[bf][ry * 128 + lane]);
            const short8 Bt1 = *reinterpret_cast<const short8*>(&two_q[bf][ry * 128 + 64 + lane]);
            acc[dy][0] = __builtin_amdgcn_mfma_f32_16x16x32_bf16(A, Bt0, acc[dy][0], 0, 0, 0);
            acc[dy][1] = __builtin_amdgcn_mfma_f32_16x16x32_bf16(A, Bt1, acc[dy][1], 0, 0, 0);
        }
    }

    const int  qq = lane >> 4;
    const int  nn2 = lane & 15;
    const int  y  = y0 + w;
    const float scale = 1.0f / (float)C_;
    #pragma unroll
    for (int dy = 0; dy < 9; ++dy) {
        #pragma unroll
        for (int ct = 0; ct < 2; ++ct) {
            floatx4 v = acc[dy][ct];
            #pragma unroll
            for (int r = 0; r < 4; ++r) {
                int m  = qq * 4 + r;
                int dx = nn2 - m + ct * 16;
                if ((unsigned)dx <= 8u) {
                    size_t o = ((size_t)(b * 81 + dy * 9 + dx) * H_ + y) * W_ + (x0 + m);
                    out[o] = v[r] * scale;
                }
            }
        }
    }
}

extern "C" void kernel_launch(void* const* d_in, const int* in_sizes, int n_in,
                              void* d_out, int out_size, void* d_ws, size_t ws_size,
                              hipStream_t stream) {
    const float* one = (const float*)d_in[0];
    const float* two = (const float*)d_in[1];
    float* out = (float*)d_out;
    const size_t need_two = (size_t)B_ * HP * WP * C_ * 2;            // 37,486,592 B
    const size_t need_one = (size_t)B_ * H_ * W_ * C_ * 2;            // 31,457,280 B
    if (d_ws != nullptr && ws_size >= need_two + need_one) {
        unsigned short* two_t = (unsigned short*)d_ws;
        unsigned short* one_t = two_t + (size_t)B_ * HP * WP * C_;
        // prep: 192 two-interior + 192 one + 37 halo-zero blocks, 640 thr each
        prep_kernel<<<dim3(421), dim3(640), 0, stream>>>(two, one, two_t, one_t);
        // corr2: 8 batches * 12 y-tiles * 10 x-tiles = 960 blocks
        corr2_kernel<<<dim3(960), dim3(512), 0, stream>>>(one_t, two_t, out);
    } else {
        corr_kernel<<<dim3(960), dim3(512), 0, stream>>>(one, two, out);
    }
}

// Round 7
// 201.520 us; speedup vs baseline: 1.1769x; 1.1769x over previous
//
#include <hip/hip_runtime.h>

#define B_  8
#define C_  128
#define H_  96
#define W_  160
#define HWp (H_ * W_)   // 15360 = one channel plane
#define PADY 4
#define HP  104         // H_ + 2*PADY
#define WP  176         // W_ + 16: halo (+8) plus slack so the 32-wide DMA window never goes OOB

typedef short  short8  __attribute__((ext_vector_type(8)));
typedef float  floatx4 __attribute__((ext_vector_type(4)));

// round-to-nearest-even fp32 -> bf16, packed pair (a low 16, b high 16)
__device__ __forceinline__ unsigned pk_bf16(float a, float b) {
    unsigned ua = __float_as_uint(a);
    unsigned ub = __float_as_uint(b);
    ua = (ua + 0x7FFFu + ((ua >> 16) & 1u)) >> 16;
    ub = (ub + 0x7FFFu + ((ub >> 16) & 1u)) & 0xFFFF0000u;
    return ua | ub;
}

// async 16B-per-lane global->LDS DMA (offset arg must be a literal constant,
// so chunk offsets are folded into the global pointer at the call site).
__device__ __forceinline__ void gload_lds16(const void* g, void* l) {
    __builtin_amdgcn_global_load_lds(
        (const __attribute__((address_space(1))) unsigned int*)g,
        (__attribute__((address_space(3))) unsigned int*)l, 16, 0, 0);
}

// ---------------------------------------------------------------------------
// Prep v4: fp32 NCHW -> bf16 NHWC via LDS corner-turn.
// Lessons: v3 showed per-plane contiguous reads are good but direct NHWC
// stores shatter lines (WRITE 103 MB); v1 showed LDS turn gives ideal writes
// but its 128B-segment reads cap at ~2.2 TB/s. v4 does contiguous 640B-per-
// plane reads AND full-line 1KB wave stores, with the turn in LDS:
//   layout lds[cp 64][x stride 164] (164 = 4 mod 32):
//   - write: ds_write_b128 of 4 consecutive x at bank 4(P+q) -> conflict-free
//   - read:  4 x ds_read_b32 gather per record part (8-way, ~2us total; cheap)
// Block = one (b, y) row, all 128 c, 640 threads (10 waves).
//   id < 768  : two rows -> two_t (shifted +4,+4)
//   id < 1536 : one rows -> one_t
//   id >=1536 : zero two_t halo (border rows + x-halo/slack columns)
// ---------------------------------------------------------------------------
__global__ __launch_bounds__(640, 1)
void prep_kernel(const float* __restrict__ two, const float* __restrict__ one,
                 unsigned short* __restrict__ two_t,
                 unsigned short* __restrict__ one_t) {
    __shared__ unsigned lds[64 * 164];     // 41,984 B -> 3 blocks/CU

    const int id  = blockIdx.x;
    const int tid = threadIdx.x;

    if (id < 1536) {
        const bool istwo = id < 768;
        const int id2 = istwo ? id : id - 768;
        const int b = id2 & 7;             // batch spread across XCDs
        const int y = id2 >> 3;            // 0..95
        const float* src = (istwo ? two : one) + ((size_t)(b * C_) * H_ + y) * W_;

        // ---- load phase: thread = (plane-pair slot p, x-quad q) ----
        const int p = tid / 40;            // 0..15
        const int q = tid - p * 40;        // 0..39 -> x = 4q..4q+3
        floatx4 l0[4], l1[4];
        #pragma unroll
        for (int it = 0; it < 4; ++it) {   // 8 dwordx4 in flight per thread
            const int P = it * 16 + p;     // c-pair 0..63
            l0[it] = *reinterpret_cast<const floatx4*>(src + (size_t)(2 * P) * HWp + 4 * q);
            l1[it] = *reinterpret_cast<const floatx4*>(src + (size_t)(2 * P + 1) * HWp + 4 * q);
        }
        #pragma unroll
        for (int it = 0; it < 4; ++it) {
            const int P = it * 16 + p;
            uint4 u;
            u.x = pk_bf16(l0[it][0], l1[it][0]);
            u.y = pk_bf16(l0[it][1], l1[it][1]);
            u.z = pk_bf16(l0[it][2], l1[it][2]);
            u.w = pk_bf16(l0[it][3], l1[it][3]);
            *reinterpret_cast<uint4*>(&lds[P * 164 + 4 * q]) = u;   // conflict-free b128
        }
        __syncthreads();

        // ---- store phase: lanes = (cp-part fast, record next) -> 1KB/wave ----
        unsigned short* dst = istwo
            ? two_t + ((size_t)(b * HP + y + PADY) * WP + 4) * C_
            : one_t + ((size_t)(b * H_ + y) * W_) * C_;
        const int part = tid & 15;         // which 4-cp quad (16B) of the record
        const int rg   = tid >> 4;         // 0..39
        #pragma unroll
        for (int is = 0; is < 4; ++is) {
            const int x = is * 40 + rg;    // record 0..159
            uint4 v;
            v.x = lds[(4 * part + 0) * 164 + x];
            v.y = lds[(4 * part + 1) * 164 + x];
            v.z = lds[(4 * part + 2) * 164 + x];
            v.w = lds[(4 * part + 3) * 164 + x];
            *reinterpret_cast<uint4*>(dst + (size_t)x * C_ + part * 8) = v;
        }
    } else {
        // ----- two_t halo zero: 23552 records (8 border rows * 176 +
        //       96 interior rows * 16 halo/slack cols, x 8 batches) -----
        const int idx = (id - 1536) * 640 + tid;
        if (idx < 23552) {
            const int b = idx / 2944;
            const int r = idx - b * 2944;
            int ypad, xp;
            if (r < 1408) {                // full border rows 0..3, 100..103
                const int rb = r / 176;
                ypad = (rb < 4) ? rb : 96 + rb;
                xp   = r - rb * 176;
            } else {                       // interior rows: cols 0..3, 164..175
                const int rr = r - 1408;
                ypad = PADY + (rr >> 4);
                const int k = rr & 15;
                xp   = (k < 4) ? k : 160 + k;
            }
            unsigned short* d = two_t + ((size_t)(b * HP + ypad) * WP + xp) * C_;
            const uint4 z{0u, 0u, 0u, 0u};
            #pragma unroll
            for (int r2 = 0; r2 < 16; ++r2)
                *reinterpret_cast<uint4*>(d + r2 * 8) = z;
        }
    }
}

// ---------------------------------------------------------------------------
// Pass 2: band-GEMM correlation, pure-DMA staging (both operands via
// global_load_lds from bf16 NHWC), counted vmcnt, raw barriers, coalesced
// LDS-staged epilogue. (unchanged — harness-verified, ~29 µs)
// ---------------------------------------------------------------------------
__global__ __launch_bounds__(512, 4)
void corr2_kernel(const unsigned short* __restrict__ one_t,
                  const unsigned short* __restrict__ two_t,
                  float* __restrict__ out) {
    __shared__ uint4 two_q[2][16 * 128];   // 32 KB x2: [ry16][ct2*64 + kg4*16 + n16]
    __shared__ uint4 one_q[2][8 * 64];     //  8 KB x2: [y8][kg4*16 + x16]  -> 80 KB total

    const int id = blockIdx.x;
    const int b  = id & 7;            // one batch per XCD
    const int jj = id >> 3;           // 0..119
    const int yt = jj % 12;
    const int xt = jj / 12;
    const int y0 = yt * 8;
    const int x0 = xt * 16;

    const int tid  = threadIdx.x;
    const int lane = tid & 63;
    const int w    = tid >> 6;        // wave id = y-row within tile
    const int kq   = lane >> 4;       // 0..3
    const int nn   = lane & 15;

    // ---- DMA source pointers (per-lane) ----
    const unsigned short* p_one =
        one_t + ((size_t)((b * H_ + y0 + w) * W_ + x0 + nn)) * C_ + kq * 8;
    const unsigned short* p_two[4];
    #pragma unroll
    for (int q = 0; q < 4; ++q) {
        const int ii = w * 4 + q;
        const int ry = ii >> 1, ct = ii & 1;
        p_two[q] = two_t + ((size_t)((b * HP + y0 + ry) * WP + x0 + ct * 16 + nn)) * C_ + kq * 8;
    }

    #define ISSUE(ck, buf) do {                                                  \
        gload_lds16(p_one + (ck) * 32, &one_q[buf][w * 64]);                     \
        _Pragma("unroll")                                                        \
        for (int q = 0; q < 4; ++q)                                              \
            gload_lds16(p_two[q] + (ck) * 32, &two_q[buf][(w * 4 + q) * 64]);    \
    } while (0)

    // raw barrier: drain own LDS ops, do NOT drain vmcnt (DMA stays in flight)
    #define BAR() asm volatile("s_waitcnt lgkmcnt(0)\n\ts_barrier" ::: "memory")

    floatx4 acc[9][2];
    #pragma unroll
    for (int dy = 0; dy < 9; ++dy) {
        acc[dy][0] = floatx4{0.f, 0.f, 0.f, 0.f};
        acc[dy][1] = floatx4{0.f, 0.f, 0.f, 0.f};
    }

    // ---- prologue: 2 chunks in flight (5 vmem ops each) ----
    ISSUE(0, 0);
    ISSUE(1, 1);

    #pragma unroll
    for (int ck = 0; ck < 4; ++ck) {
        const int cur = ck & 1;
        if (ck < 3) asm volatile("s_waitcnt vmcnt(5)" ::: "memory");
        else        asm volatile("s_waitcnt vmcnt(0)" ::: "memory");
        BAR();   // all waves' DMAs for chunk ck have landed -> safe to read

        const short8 A = *reinterpret_cast<const short8*>(&one_q[cur][w * 64 + lane]);
        #pragma unroll
        for (int dy = 0; dy < 9; ++dy) {
            const int ry = w + dy;
            const short8 Bt0 = *reinterpret_cast<const short8*>(&two_q[cur][ry * 128 + lane]);
            const short8 Bt1 = *reinterpret_cast<const short8*>(&two_q[cur][ry * 128 + 64 + lane]);
            acc[dy][0] = __builtin_amdgcn_mfma_f32_16x16x32_bf16(A, Bt0, acc[dy][0], 0, 0, 0);
            acc[dy][1] = __builtin_amdgcn_mfma_f32_16x16x32_bf16(A, Bt1, acc[dy][1], 0, 0, 0);
        }
        BAR();   // all reads of buf[cur] complete before anyone refills it

        if (ck < 2) ISSUE(ck + 2, cur);
    }

    // ---- epilogue: stage into LDS (overlaid on dead two_q), store coalesced ----
    __syncthreads();                               // everyone done with two_q
    float* ep = reinterpret_cast<float*>(&two_q[0][0]);   // 81*130*4 = 42 KB < 64 KB
    const float scale = 1.0f / (float)C_;
    #pragma unroll
    for (int dy = 0; dy < 9; ++dy) {
        #pragma unroll
        for (int ct = 0; ct < 2; ++ct) {
            floatx4 v = acc[dy][ct];
            #pragma unroll
            for (int r = 0; r < 4; ++r) {
                const int m  = kq * 4 + r;
                const int dx = nn - m + ct * 16;
                if ((unsigned)dx <= 8u)
                    ep[(dy * 9 + dx) * 130 + w * 16 + m] = v[r] * scale;
            }
        }
    }
    __syncthreads();
    // 81 planes * 128 floats = 10368 dwords; lanes cover x fastest -> full 64B lines
    #pragma unroll
    for (int i = 0; i < 21; ++i) {
        const int g = tid + i * 512;
        if (g < 81 * 128) {
            const int p   = g >> 7;
            const int loc = g & 127;               // yy*16 + xx
            const int yy  = loc >> 4, xx = loc & 15;
            out[((size_t)(b * 81 + p) * H_ + y0 + yy) * W_ + x0 + xx] = ep[p * 130 + loc];
        }
    }
    #undef ISSUE
    #undef BAR
}

// ---------------------------------------------------------------------------
// Fallback: harness-verified single-pass kernel (used if workspace too small)
// ---------------------------------------------------------------------------
__global__ __launch_bounds__(512, 2)
void corr_kernel(const float* __restrict__ one, const float* __restrict__ two,
                 float* __restrict__ out) {
    __shared__ uint4 one_q[2][8 * 64];
    __shared__ uint4 two_q[2][16 * 128];

    const int id = blockIdx.x;
    const int b  = id & 7;
    const int jj = id >> 3;
    const int yt = jj % 12;
    const int xt = jj / 12;
    const int y0 = yt * 8;
    const int x0 = xt * 16;

    const int tid  = threadIdx.x;
    const int lane = tid & 63;
    const int w    = tid >> 6;

    const int o_xl  = tid & 15;
    const int o_yl  = (tid >> 4) & 7;
    const int o_kg  = tid >> 7;
    const int o_rec = o_yl * 64 + o_kg * 16 + o_xl;

    const int t_cx  = tid & 31;
    const int t_ry  = tid >> 5;
    const int t_y   = y0 - 4 + t_ry;
    const int t_gx  = x0 - 4 + t_cx;
    const bool t_valid = ((unsigned)t_y < H_) && ((unsigned)t_gx < W_) && (t_cx < 24);
    const int t_rec = t_ry * 128 + (t_cx >> 4) * 64 + (t_cx & 15);

    const float* o_base = one + ((size_t)(b * C_ + 8 * o_kg) * H_ + (y0 + o_yl)) * W_ + (x0 + o_xl);
    const float* t_base = two + ((size_t)(b * C_) * H_ + t_y) * W_ + t_gx;

    float ro[8];
    float rt[32];

    floatx4 acc[9][2];
    #pragma unroll
    for (int dy = 0; dy < 9; ++dy) {
        acc[dy][0] = floatx4{0.f, 0.f, 0.f, 0.f};
        acc[dy][1] = floatx4{0.f, 0.f, 0.f, 0.f};
    }

    {
        const float* p1 = o_base;
        #pragma unroll
        for (int i = 0; i < 8; ++i) ro[i] = p1[(size_t)i * HWp];
        if (t_valid) {
            const float* p2 = t_base;
            #pragma unroll
            for (int i = 0; i < 32; ++i) rt[i] = p2[(size_t)i * HWp];
        } else {
            #pragma unroll
            for (int i = 0; i < 32; ++i) rt[i] = 0.f;
        }
    }

    #pragma unroll
    for (int ck = 0; ck < 4; ++ck) {
        const int bf = ck & 1;
        {
            uint4 v;
            v.x = pk_bf16(ro[0], ro[1]);
            v.y = pk_bf16(ro[2], ro[3]);
            v.z = pk_bf16(ro[4], ro[5]);
            v.w = pk_bf16(ro[6], ro[7]);
            one_q[bf][o_rec] = v;
            #pragma unroll
            for (int kg = 0; kg < 4; ++kg) {
                uint4 u;
                u.x = pk_bf16(rt[kg * 8 + 0], rt[kg * 8 + 1]);
                u.y = pk_bf16(rt[kg * 8 + 2], rt[kg * 8 + 3]);
                u.z = pk_bf16(rt[kg * 8 + 4], rt[kg * 8 + 5]);
                u.w = pk_bf16(rt[kg * 8 + 6], rt[kg * 8 + 7]);
                two_q[bf][t_rec + kg * 16] = u;
            }
        }
        __syncthreads();

        if (ck < 3) {
            const float* p1 = o_base + (size_t)((ck + 1) * 32) * HWp;
            #pragma unroll
            for (int i = 0; i < 8; ++i) ro[i] = p1[(size_t)i * HWp];
            if (t_valid) {
                const float* p2 = t_base + (size_t)((ck + 1) * 32) * HWp;
                #pragma unroll
                for (int i = 0; i < 32; ++i) rt[i] = p2[(size_t)i * HWp];
            }
        }

        const short8 A = *reinterpret_cast<const short8*>(&one_q[bf][w * 64 + lane]);
        #pragma unroll
        for (int dy = 0; dy < 9; ++dy) {
            const int ry = w + dy;
            const short8 Bt0 = *reinterpret_cast<const short8*>(&two_q[bf][ry * 128 + lane]);
            const short8 Bt1 = *reinterpret_cast<const short8*>(&two_q[bf][ry * 128 + 64 + lane]);
            acc[dy][0] = __builtin_amdgcn_mfma_f32_16x16x32_bf16(A, Bt0, acc[dy][0], 0, 0, 0);
            acc[dy][1] = __builtin_amdgcn_mfma_f32_16x16x32_bf16(A, Bt1, acc[dy][1], 0, 0, 0);
        }
    }

    const int  qq = lane >> 4;
    const int  nn2 = lane & 15;
    const int  y  = y0 + w;
    const float scale = 1.0f / (float)C_;
    #pragma unroll
    for (int dy = 0; dy < 9; ++dy) {
        #pragma unroll
        for (int ct = 0; ct < 2; ++ct) {
            floatx4 v = acc[dy][ct];
            #pragma unroll
            for (int r = 0; r < 4; ++r) {
                int m  = qq * 4 + r;
                int dx = nn2 - m + ct * 16;
                if ((unsigned)dx <= 8u) {
                    size_t o = ((size_t)(b * 81 + dy * 9 + dx) * H_ + y) * W_ + (x0 + m);
                    out[o] = v[r] * scale;
                }
            }
        }
    }
}

extern "C" void kernel_launch(void* const* d_in, const int* in_sizes, int n_in,
                              void* d_out, int out_size, void* d_ws, size_t ws_size,
                              hipStream_t stream) {
    const float* one = (const float*)d_in[0];
    const float* two = (const float*)d_in[1];
    float* out = (float*)d_out;
    const size_t need_two = (size_t)B_ * HP * WP * C_ * 2;            // 37,486,592 B
    const size_t need_one = (size_t)B_ * H_ * W_ * C_ * 2;            // 31,457,280 B
    if (d_ws != nullptr && ws_size >= need_two + need_one) {
        unsigned short* two_t = (unsigned short*)d_ws;
        unsigned short* one_t = two_t + (size_t)B_ * HP * WP * C_;
        // prep: 768 two-rows + 768 one-rows + 37 halo-zero blocks, 640 thr each
        prep_kernel<<<dim3(1573), dim3(640), 0, stream>>>(two, one, two_t, one_t);
        // corr2: 8 batches * 12 y-tiles * 10 x-tiles = 960 blocks
        corr2_kernel<<<dim3(960), dim3(512), 0, stream>>>(one_t, two_t, out);
    } else {
        corr_kernel<<<dim3(960), dim3(512), 0, stream>>>(one, two, out);
    }
}

// Round 8
// 201.475 us; speedup vs baseline: 1.1771x; 1.0002x over previous
//
#include <hip/hip_runtime.h>

#define B_  8
#define C_  128
#define H_  96
#define W_  160
#define HWp (H_ * W_)   // 15360 = one channel plane
#define PADY 4
#define HP  104         // H_ + 2*PADY
#define WP  176         // W_ + 16: halo (+8) plus slack so the 32-wide DMA window never goes OOB

typedef short  short8  __attribute__((ext_vector_type(8)));
typedef float  floatx4 __attribute__((ext_vector_type(4)));

// round-to-nearest-even fp32 -> bf16, packed pair (a low 16, b high 16)
__device__ __forceinline__ unsigned pk_bf16(float a, float b) {
    unsigned ua = __float_as_uint(a);
    unsigned ub = __float_as_uint(b);
    ua = (ua + 0x7FFFu + ((ua >> 16) & 1u)) >> 16;
    ub = (ub + 0x7FFFu + ((ub >> 16) & 1u)) & 0xFFFF0000u;
    return ua | ub;
}

// async 16B-per-lane global->LDS DMA (offset arg must be a literal constant,
// so chunk offsets are folded into the global pointer at the call site).
__device__ __forceinline__ void gload_lds16(const void* g, void* l) {
    __builtin_amdgcn_global_load_lds(
        (const __attribute__((address_space(1))) unsigned int*)g,
        (__attribute__((address_space(3))) unsigned int*)l, 16, 0, 0);
}

// ---------------------------------------------------------------------------
// Prep v5: fp32 NCHW -> bf16 NHWC, software-pipelined LDS corner-turn.
// Lessons: v1..v4 all bottomed at ~2 TB/s because each block is a shallow
// {load -> barrier -> store} lifecycle: nothing covers HBM latency between
// phases, and the compiler register-minimizes the "in-flight" loads away
// (v4: VGPR=20 with 8 declared float4!). v5: each block processes THREE
// 64c x 160px half-row units, software-pipelined: unit k+1's 10 float2
// loads are issued before unit k's pack/store, pinned by counted
// s_waitcnt vmcnt(N) asm (memory clobber stops the compiler sinking the
// prefetch). Ping-pong register sets (static indexing) force the payload
// live -> real 10-deep ILP + 1-unit lookahead.
// LDS [x 160][cp 32] stride 33: pack-write bank (2q+cp)%32 and store-read
// bank (x+2pt)%32 are both exactly 2-way (free). Stores: 16 lanes x 8B =
// 128B contiguous per record, 4 records/instr -> full aligned L2 lines.
//   id < 1024 : 3 transpose units each (3072 = 1536 rows x 2 c-halves)
//   id >= 1024: 46 halo-zero blocks (23552 records = 46 x 512 exactly)
// ---------------------------------------------------------------------------
__device__ __forceinline__ void unit_ptrs(int u, const float* two, const float* one,
                                          unsigned short* two_t, unsigned short* one_t,
                                          const float*& s, unsigned short*& d) {
    const int uu    = (u < 1536) ? u : u - 1536;
    const int chalf = uu & 1;
    const int row   = uu >> 1;
    const int b     = row & 7;        // batch spread across XCDs
    const int y     = row >> 3;       // 0..95
    if (u < 1536) {
        s = two + ((size_t)(b * C_ + chalf * 64) * H_ + y) * W_;
        d = two_t + ((size_t)(b * HP + y + PADY) * WP + 4) * C_ + chalf * 64;
    } else {
        s = one + ((size_t)(b * C_ + chalf * 64) * H_ + y) * W_;
        d = one_t + ((size_t)(b * H_ + y) * W_) * C_ + chalf * 64;
    }
}

__global__ __launch_bounds__(512, 6)
void prep_kernel(const float* __restrict__ two, const float* __restrict__ one,
                 unsigned short* __restrict__ two_t,
                 unsigned short* __restrict__ one_t) {
    __shared__ unsigned lds[160 * 33];     // 21,120 B -> LDS allows 7 blocks/CU

    const int id  = blockIdx.x;
    const int tid = threadIdx.x;

    if (id < 1024) {
        const int cp = tid >> 4;           // c-pair 0..31 (channels 2cp, 2cp+1 of the half)
        const int q  = tid & 15;           // x-slot: px {32j + 2q, +1}, j = 0..4
        const size_t po = (size_t)(2 * cp) * HWp;

        const float* s0; unsigned short* d0;
        const float* s1; unsigned short* d1;
        const float* s2; unsigned short* d2;
        unit_ptrs(id * 3 + 0, two, one, two_t, one_t, s0, d0);
        unit_ptrs(id * 3 + 1, two, one, two_t, one_t, s1, d1);
        unit_ptrs(id * 3 + 2, two, one, two_t, one_t, s2, d2);

        float2 A0[5], A1[5], B0r[5], B1r[5];

        #define LOADU(r0, r1, S) do {                                            \
            _Pragma("unroll")                                                    \
            for (int j = 0; j < 5; ++j) {                                        \
                const int x = 32 * j + 2 * q;                                    \
                r0[j] = *reinterpret_cast<const float2*>((S) + po + x);          \
                r1[j] = *reinterpret_cast<const float2*>((S) + po + HWp + x);    \
            } } while (0)

        #define PACKU(r0, r1) do {                                               \
            _Pragma("unroll")                                                    \
            for (int j = 0; j < 5; ++j) {                                        \
                const int x = 32 * j + 2 * q;                                    \
                lds[x * 33 + cp]       = pk_bf16(r0[j].x, r1[j].x);              \
                lds[(x + 1) * 33 + cp] = pk_bf16(r0[j].y, r1[j].y);              \
            } } while (0)

        #define STOREU(D) do {                                                   \
            _Pragma("unroll")                                                    \
            for (int i = 0; i < 5; ++i) {                                        \
                const int g = tid + i * 512;                                     \
                const int x = g >> 4, pt = g & 15;                               \
                uint2 v;                                                         \
                v.x = lds[x * 33 + 2 * pt];                                      \
                v.y = lds[x * 33 + 2 * pt + 1];                                  \
                *reinterpret_cast<uint2*>((D) + (size_t)x * C_ + pt * 4) = v;    \
            } } while (0)

        // pipeline: queue order [A:10][B:10][ST0:5][A':10][ST1:5][ST2:5]
        LOADU(A0, A1, s0);
        LOADU(B0r, B1r, s1);
        asm volatile("s_waitcnt vmcnt(10)" ::: "memory");   // A done; B in flight
        PACKU(A0, A1);
        __syncthreads();
        STOREU(d0);
        LOADU(A0, A1, s2);                                  // reuse A regs for unit 2
        __syncthreads();                                    // LDS reads done before repack
        asm volatile("s_waitcnt vmcnt(15)" ::: "memory");   // B done (newer: 5 st + 10 ld)
        PACKU(B0r, B1r);
        __syncthreads();
        STOREU(d1);
        __syncthreads();
        asm volatile("s_waitcnt vmcnt(5)" ::: "memory");    // unit-2 loads done (newer: 5 st)
        PACKU(A0, A1);
        __syncthreads();
        STOREU(d2);
        #undef LOADU
        #undef PACKU
        #undef STOREU
    } else {
        // ----- two_t halo zero: 23552 records (8 border rows * 176 +
        //       96 interior rows * 16 halo/slack cols, x 8 batches) -----
        const int idx = (id - 1024) * 512 + tid;            // 46*512 = 23552 exactly
        const int b = idx / 2944;
        const int r = idx - b * 2944;
        int ypad, xp;
        if (r < 1408) {                    // full border rows 0..3, 100..103
            const int rb = r / 176;
            ypad = (rb < 4) ? rb : 96 + rb;
            xp   = r - rb * 176;
        } else {                           // interior rows: cols 0..3, 164..175
            const int rr = r - 1408;
            ypad = PADY + (rr >> 4);
            const int k = rr & 15;
            xp   = (k < 4) ? k : 160 + k;
        }
        unsigned short* d = two_t + ((size_t)(b * HP + ypad) * WP + xp) * C_;
        const uint4 z{0u, 0u, 0u, 0u};
        #pragma unroll
        for (int r2 = 0; r2 < 16; ++r2)
            *reinterpret_cast<uint4*>(d + r2 * 8) = z;
    }
}

// ---------------------------------------------------------------------------
// Pass 2: band-GEMM correlation, pure-DMA staging (both operands via
// global_load_lds from bf16 NHWC), counted vmcnt, raw barriers, coalesced
// LDS-staged epilogue. (unchanged — harness-verified, ~29 µs)
// ---------------------------------------------------------------------------
__global__ __launch_bounds__(512, 4)
void corr2_kernel(const unsigned short* __restrict__ one_t,
                  const unsigned short* __restrict__ two_t,
                  float* __restrict__ out) {
    __shared__ uint4 two_q[2][16 * 128];   // 32 KB x2: [ry16][ct2*64 + kg4*16 + n16]
    __shared__ uint4 one_q[2][8 * 64];     //  8 KB x2: [y8][kg4*16 + x16]  -> 80 KB total

    const int id = blockIdx.x;
    const int b  = id & 7;            // one batch per XCD
    const int jj = id >> 3;           // 0..119
    const int yt = jj % 12;
    const int xt = jj / 12;
    const int y0 = yt * 8;
    const int x0 = xt * 16;

    const int tid  = threadIdx.x;
    const int lane = tid & 63;
    const int w    = tid >> 6;        // wave id = y-row within tile
    const int kq   = lane >> 4;       // 0..3
    const int nn   = lane & 15;

    // ---- DMA source pointers (per-lane) ----
    const unsigned short* p_one =
        one_t + ((size_t)((b * H_ + y0 + w) * W_ + x0 + nn)) * C_ + kq * 8;
    const unsigned short* p_two[4];
    #pragma unroll
    for (int q = 0; q < 4; ++q) {
        const int ii = w * 4 + q;
        const int ry = ii >> 1, ct = ii & 1;
        p_two[q] = two_t + ((size_t)((b * HP + y0 + ry) * WP + x0 + ct * 16 + nn)) * C_ + kq * 8;
    }

    #define ISSUE(ck, buf) do {                                                  \
        gload_lds16(p_one + (ck) * 32, &one_q[buf][w * 64]);                     \
        _Pragma("unroll")                                                        \
        for (int q = 0; q < 4; ++q)                                              \
            gload_lds16(p_two[q] + (ck) * 32, &two_q[buf][(w * 4 + q) * 64]);    \
    } while (0)

    // raw barrier: drain own LDS ops, do NOT drain vmcnt (DMA stays in flight)
    #define BAR() asm volatile("s_waitcnt lgkmcnt(0)\n\ts_barrier" ::: "memory")

    floatx4 acc[9][2];
    #pragma unroll
    for (int dy = 0; dy < 9; ++dy) {
        acc[dy][0] = floatx4{0.f, 0.f, 0.f, 0.f};
        acc[dy][1] = floatx4{0.f, 0.f, 0.f, 0.f};
    }

    // ---- prologue: 2 chunks in flight (5 vmem ops each) ----
    ISSUE(0, 0);
    ISSUE(1, 1);

    #pragma unroll
    for (int ck = 0; ck < 4; ++ck) {
        const int cur = ck & 1;
        if (ck < 3) asm volatile("s_waitcnt vmcnt(5)" ::: "memory");
        else        asm volatile("s_waitcnt vmcnt(0)" ::: "memory");
        BAR();   // all waves' DMAs for chunk ck have landed -> safe to read

        const short8 A = *reinterpret_cast<const short8*>(&one_q[cur][w * 64 + lane]);
        #pragma unroll
        for (int dy = 0; dy < 9; ++dy) {
            const int ry = w + dy;
            const short8 Bt0 = *reinterpret_cast<const short8*>(&two_q[cur][ry * 128 + lane]);
            const short8 Bt1 = *reinterpret_cast<const short8*>(&two_q[cur][ry * 128 + 64 + lane]);
            acc[dy][0] = __builtin_amdgcn_mfma_f32_16x16x32_bf16(A, Bt0, acc[dy][0], 0, 0, 0);
            acc[dy][1] = __builtin_amdgcn_mfma_f32_16x16x32_bf16(A, Bt1, acc[dy][1], 0, 0, 0);
        }
        BAR();   // all reads of buf[cur] complete before anyone refills it

        if (ck < 2) ISSUE(ck + 2, cur);
    }

    // ---- epilogue: stage into LDS (overlaid on dead two_q), store coalesced ----
    __syncthreads();                               // everyone done with two_q
    float* ep = reinterpret_cast<float*>(&two_q[0][0]);   // 81*130*4 = 42 KB < 64 KB
    const float scale = 1.0f / (float)C_;
    #pragma unroll
    for (int dy = 0; dy < 9; ++dy) {
        #pragma unroll
        for (int ct = 0; ct < 2; ++ct) {
            floatx4 v = acc[dy][ct];
            #pragma unroll
            for (int r = 0; r < 4; ++r) {
                const int m  = kq * 4 + r;
                const int dx = nn - m + ct * 16;
                if ((unsigned)dx <= 8u)
                    ep[(dy * 9 + dx) * 130 + w * 16 + m] = v[r] * scale;
            }
        }
    }
    __syncthreads();
    // 81 planes * 128 floats = 10368 dwords; lanes cover x fastest -> full 64B lines
    #pragma unroll
    for (int i = 0; i < 21; ++i) {
        const int g = tid + i * 512;
        if (g < 81 * 128) {
            const int p   = g >> 7;
            const int loc = g & 127;               // yy*16 + xx
            const int yy  = loc >> 4, xx = loc & 15;
            out[((size_t)(b * 81 + p) * H_ + y0 + yy) * W_ + x0 + xx] = ep[p * 130 + loc];
        }
    }
    #undef ISSUE
    #undef BAR
}

// ---------------------------------------------------------------------------
// Fallback: harness-verified single-pass kernel (used if workspace too small)
// ---------------------------------------------------------------------------
__global__ __launch_bounds__(512, 2)
void corr_kernel(const float* __restrict__ one, const float* __restrict__ two,
                 float* __restrict__ out) {
    __shared__ uint4 one_q[2][8 * 64];
    __shared__ uint4 two_q[2][16 * 128];

    const int id = blockIdx.x;
    const int b  = id & 7;
    const int jj = id >> 3;
    const int yt = jj % 12;
    const int xt = jj / 12;
    const int y0 = yt * 8;
    const int x0 = xt * 16;

    const int tid  = threadIdx.x;
    const int lane = tid & 63;
    const int w    = tid >> 6;

    const int o_xl  = tid & 15;
    const int o_yl  = (tid >> 4) & 7;
    const int o_kg  = tid >> 7;
    const int o_rec = o_yl * 64 + o_kg * 16 + o_xl;

    const int t_cx  = tid & 31;
    const int t_ry  = tid >> 5;
    const int t_y   = y0 - 4 + t_ry;
    const int t_gx  = x0 - 4 + t_cx;
    const bool t_valid = ((unsigned)t_y < H_) && ((unsigned)t_gx < W_) && (t_cx < 24);
    const int t_rec = t_ry * 128 + (t_cx >> 4) * 64 + (t_cx & 15);

    const float* o_base = one + ((size_t)(b * C_ + 8 * o_kg) * H_ + (y0 + o_yl)) * W_ + (x0 + o_xl);
    const float* t_base = two + ((size_t)(b * C_) * H_ + t_y) * W_ + t_gx;

    float ro[8];
    float rt[32];

    floatx4 acc[9][2];
    #pragma unroll
    for (int dy = 0; dy < 9; ++dy) {
        acc[dy][0] = floatx4{0.f, 0.f, 0.f, 0.f};
        acc[dy][1] = floatx4{0.f, 0.f, 0.f, 0.f};
    }

    {
        const float* p1 = o_base;
        #pragma unroll
        for (int i = 0; i < 8; ++i) ro[i] = p1[(size_t)i * HWp];
        if (t_valid) {
            const float* p2 = t_base;
            #pragma unroll
            for (int i = 0; i < 32; ++i) rt[i] = p2[(size_t)i * HWp];
        } else {
            #pragma unroll
            for (int i = 0; i < 32; ++i) rt[i] = 0.f;
        }
    }

    #pragma unroll
    for (int ck = 0; ck < 4; ++ck) {
        const int bf = ck & 1;
        {
            uint4 v;
            v.x = pk_bf16(ro[0], ro[1]);
            v.y = pk_bf16(ro[2], ro[3]);
            v.z = pk_bf16(ro[4], ro[5]);
            v.w = pk_bf16(ro[6], ro[7]);
            one_q[bf][o_rec] = v;
            #pragma unroll
            for (int kg = 0; kg < 4; ++kg) {
                uint4 u;
                u.x = pk_bf16(rt[kg * 8 + 0], rt[kg * 8 + 1]);
                u.y = pk_bf16(rt[kg * 8 + 2], rt[kg * 8 + 3]);
                u.z = pk_bf16(rt[kg * 8 + 4], rt[kg * 8 + 5]);
                u.w = pk_bf16(rt[kg * 8 + 6], rt[kg * 8 + 7]);
                two_q[bf][t_rec + kg * 16] = u;
            }
        }
        __syncthreads();

        if (ck < 3) {
            const float* p1 = o_base + (size_t)((ck + 1) * 32) * HWp;
            #pragma unroll
            for (int i = 0; i < 8; ++i) ro[i] = p1[(size_t)i * HWp];
            if (t_valid) {
                const float* p2 = t_base + (size_t)((ck + 1) * 32) * HWp;
                #pragma unroll
                for (int i = 0; i < 32; ++i) rt[i] = p2[(size_t)i * HWp];
            }
        }

        const short8 A = *reinterpret_cast<const short8*>(&one_q[bf][w * 64 + lane]);
        #pragma unroll
        for (int dy = 0; dy < 9; ++dy) {
            const int ry = w + dy;
            const short8 Bt0 = *reinterpret_cast<const short8*>(&two_q[bf][ry * 128 + lane]);
            const short8 Bt1 = *reinterpret_cast<const short8*>(&two_q[bf][ry * 128 + 64 + lane]);
            acc[dy][0] = __builtin_amdgcn_mfma_f32_16x16x32_bf16(A, Bt0, acc[dy][0], 0, 0, 0);
            acc[dy][1] = __builtin_amdgcn_mfma_f32_16x16x32_bf16(A, Bt1, acc[dy][1], 0, 0, 0);
        }
    }

    const int  qq = lane >> 4;
    const int  nn2 = lane & 15;
    const int  y  = y0 + w;
    const float scale = 1.0f / (float)C_;
    #pragma unroll
    for (int dy = 0; dy < 9; ++dy) {
        #pragma unroll
        for (int ct = 0; ct < 2; ++ct) {
            floatx4 v = acc[dy][ct];
            #pragma unroll
            for (int r = 0; r < 4; ++r) {
                int m  = qq * 4 + r;
                int dx = nn2 - m + ct * 16;
                if ((unsigned)dx <= 8u) {
                    size_t o = ((size_t)(b * 81 + dy * 9 + dx) * H_ + y) * W_ + (x0 + m);
                    out[o] = v[r] * scale;
                }
            }
        }
    }
}

extern "C" void kernel_launch(void* const* d_in, const int* in_sizes, int n_in,
                              void* d_out, int out_size, void* d_ws, size_t ws_size,
                              hipStream_t stream) {
    const float* one = (const float*)d_in[0];
    const float* two = (const float*)d_in[1];
    float* out = (float*)d_out;
    const size_t need_two = (size_t)B_ * HP * WP * C_ * 2;            // 37,486,592 B
    const size_t need_one = (size_t)B_ * H_ * W_ * C_ * 2;            // 31,457,280 B
    if (d_ws != nullptr && ws_size >= need_two + need_one) {
        unsigned short* two_t = (unsigned short*)d_ws;
        unsigned short* one_t = two_t + (size_t)B_ * HP * WP * C_;
        // prep: 1024 pipelined 3-unit blocks + 46 halo-zero blocks, 512 thr each
        prep_kernel<<<dim3(1070), dim3(512), 0, stream>>>(two, one, two_t, one_t);
        // corr2: 8 batches * 12 y-tiles * 10 x-tiles = 960 blocks
        corr2_kernel<<<dim3(960), dim3(512), 0, stream>>>(one_t, two_t, out);
    } else {
        corr_kernel<<<dim3(960), dim3(512), 0, stream>>>(one, two, out);
    }
}

// Round 9
// 200.254 us; speedup vs baseline: 1.1843x; 1.0061x over previous
//
#include <hip/hip_runtime.h>

#define B_  8
#define C_  128
#define H_  96
#define W_  160
#define HWp (H_ * W_)   // 15360 = one channel plane
#define PADY 4
#define HP  104         // H_ + 2*PADY
#define WP  176         // W_ + 16: halo (+8) plus slack so the 32-wide DMA window never goes OOB

typedef short  short8  __attribute__((ext_vector_type(8)));
typedef float  floatx4 __attribute__((ext_vector_type(4)));

// round-to-nearest-even fp32 -> bf16, packed pair (a low 16, b high 16)
__device__ __forceinline__ unsigned pk_bf16(float a, float b) {
    unsigned ua = __float_as_uint(a);
    unsigned ub = __float_as_uint(b);
    ua = (ua + 0x7FFFu + ((ua >> 16) & 1u)) >> 16;
    ub = (ub + 0x7FFFu + ((ub >> 16) & 1u)) & 0xFFFF0000u;
    return ua | ub;
}

// async 16B-per-lane global->LDS DMA (offset arg must be a literal constant,
// so chunk offsets are folded into the global pointer at the call site).
__device__ __forceinline__ void gload_lds16(const void* g, void* l) {
    __builtin_amdgcn_global_load_lds(
        (const __attribute__((address_space(1))) unsigned int*)g,
        (__attribute__((address_space(3))) unsigned int*)l, 16, 0, 0);
}

// ---------------------------------------------------------------------------
// Prep v6: fp32 NCHW -> bf16 NHWC, v1's proven two-phase LDS turn, quartered.
// Evidence across v1..v5: block COUNT (inter-block phase overlap), not
// intra-block pipelining, is what hides HBM latency (3200 blk = 61us,
// 1573/1070 blk = 71us, 421 blk = 101us). v6: block = (b, row, c-quarter
// of 32 channels), 256 threads, 21KB LDS -> 6400 blocks, up to 7/CU.
// LDS stride 33: load-phase b32 writes bank 4q+k+c2 (<=2-way, free) and
// store-phase b32 reads bank (l>>2)+8(l&3) (bijective mod 32) — v1's 3.44M
// conflict cycles -> ~0. Stores: 4 consecutive lanes fill each 64B line
// within one instruction (v3-vs-v4 proven requirement).
//   id < 3328 : two rows (b,ypad,cq) -> two_t (border rows zero-fill)
//   id >=3328 : one rows (b,y,cq)    -> one_t
// ---------------------------------------------------------------------------
__global__ __launch_bounds__(256, 8)
void prep_kernel(const float* __restrict__ two, const float* __restrict__ one,
                 unsigned short* __restrict__ two_t,
                 unsigned short* __restrict__ one_t) {
    __shared__ float lds[160 * 33];        // 21,120 B -> 7 blocks/CU by LDS

    const int id  = blockIdx.x;
    const int tid = threadIdx.x;

    if (id < 3328) {
        // ----- two path: (b, ypad, cq) -----
        const int b    = id & 7;           // batch spread across XCDs
        const int r    = id >> 3;          // 0..415
        const int ypad = r % HP;           // 0..103
        const int cq   = r / HP;           // 0..3
        unsigned short* dstrow = two_t + (size_t)(b * HP + ypad) * WP * C_ + cq * 32;

        if (ypad < PADY || ypad >= PADY + H_) {        // border rows: zeros
            const uint4 z{0u, 0u, 0u, 0u};
            #pragma unroll
            for (int i = 0; i < 3; ++i) {
                const int g = tid + i * 256;           // unit = 16B part of 64B quarter
                if (g < WP * 4) {
                    const int xp = g >> 2, part = g & 3;
                    *reinterpret_cast<uint4*>(dstrow + (size_t)xp * C_ + part * 8) = z;
                }
            }
            return;
        }

        const int y  = ypad - PADY;
        const int c2 = tid >> 3;           // 0..31 local channel
        const int q  = tid & 7;            // x-quad slot
        const float* src = two + ((size_t)(b * C_ + cq * 32 + c2) * H_ + y) * W_;
        #pragma unroll
        for (int j = 0; j < 5; ++j) {      // 5 float4 in flight per thread (v1-proven)
            const int x0 = (j * 8 + q) * 4;
            const floatx4 v = *reinterpret_cast<const floatx4*>(&src[x0]);
            lds[(x0 + 0) * 33 + c2] = v[0];
            lds[(x0 + 1) * 33 + c2] = v[1];
            lds[(x0 + 2) * 33 + c2] = v[2];
            lds[(x0 + 3) * 33 + c2] = v[3];
        }
        __syncthreads();
        #pragma unroll
        for (int i = 0; i < 3; ++i) {
            const int g = tid + i * 256;
            if (g < WP * 4) {
                const int xp = g >> 2, part = g & 3;
                const int xs = xp - 4;
                uint4 v{0u, 0u, 0u, 0u};
                if ((unsigned)xs < (unsigned)W_) {
                    const float* p = &lds[xs * 33 + part * 8];
                    v.x = pk_bf16(p[0], p[1]);
                    v.y = pk_bf16(p[2], p[3]);
                    v.z = pk_bf16(p[4], p[5]);
                    v.w = pk_bf16(p[6], p[7]);
                }
                // 4 consecutive lanes (parts 0-3, same xp) fill one 64B line
                *reinterpret_cast<uint4*>(dstrow + (size_t)xp * C_ + part * 8) = v;
            }
        }
    } else {
        // ----- one path: (b, y, cq), no padding -----
        const int id2 = id - 3328;
        const int b   = id2 & 7;
        const int r   = id2 >> 3;          // 0..383
        const int y   = r % H_;
        const int cq  = r / H_;
        unsigned short* dstrow = one_t + (size_t)(b * H_ + y) * W_ * C_ + cq * 32;

        const int c2 = tid >> 3;
        const int q  = tid & 7;
        const float* src = one + ((size_t)(b * C_ + cq * 32 + c2) * H_ + y) * W_;
        #pragma unroll
        for (int j = 0; j < 5; ++j) {
            const int x0 = (j * 8 + q) * 4;
            const floatx4 v = *reinterpret_cast<const floatx4*>(&src[x0]);
            lds[(x0 + 0) * 33 + c2] = v[0];
            lds[(x0 + 1) * 33 + c2] = v[1];
            lds[(x0 + 2) * 33 + c2] = v[2];
            lds[(x0 + 3) * 33 + c2] = v[3];
        }
        __syncthreads();
        #pragma unroll
        for (int i = 0; i < 3; ++i) {
            const int g = tid + i * 256;
            if (g < W_ * 4) {
                const int x = g >> 2, part = g & 3;
                const float* p = &lds[x * 33 + part * 8];
                uint4 v;
                v.x = pk_bf16(p[0], p[1]);
                v.y = pk_bf16(p[2], p[3]);
                v.z = pk_bf16(p[4], p[5]);
                v.w = pk_bf16(p[6], p[7]);
                *reinterpret_cast<uint4*>(dstrow + (size_t)x * C_ + part * 8) = v;
            }
        }
    }
}

// ---------------------------------------------------------------------------
// Pass 2: band-GEMM correlation, pure-DMA staging (both operands via
// global_load_lds from bf16 NHWC), counted vmcnt, raw barriers, coalesced
// LDS-staged epilogue. (unchanged — harness-verified, ~30 µs)
// ---------------------------------------------------------------------------
__global__ __launch_bounds__(512, 4)
void corr2_kernel(const unsigned short* __restrict__ one_t,
                  const unsigned short* __restrict__ two_t,
                  float* __restrict__ out) {
    __shared__ uint4 two_q[2][16 * 128];   // 32 KB x2: [ry16][ct2*64 + kg4*16 + n16]
    __shared__ uint4 one_q[2][8 * 64];     //  8 KB x2: [y8][kg4*16 + x16]  -> 80 KB total

    const int id = blockIdx.x;
    const int b  = id & 7;            // one batch per XCD
    const int jj = id >> 3;           // 0..119
    const int yt = jj % 12;
    const int xt = jj / 12;
    const int y0 = yt * 8;
    const int x0 = xt * 16;

    const int tid  = threadIdx.x;
    const int lane = tid & 63;
    const int w    = tid >> 6;        // wave id = y-row within tile
    const int kq   = lane >> 4;       // 0..3
    const int nn   = lane & 15;

    // ---- DMA source pointers (per-lane) ----
    const unsigned short* p_one =
        one_t + ((size_t)((b * H_ + y0 + w) * W_ + x0 + nn)) * C_ + kq * 8;
    const unsigned short* p_two[4];
    #pragma unroll
    for (int q = 0; q < 4; ++q) {
        const int ii = w * 4 + q;
        const int ry = ii >> 1, ct = ii & 1;
        p_two[q] = two_t + ((size_t)((b * HP + y0 + ry) * WP + x0 + ct * 16 + nn)) * C_ + kq * 8;
    }

    #define ISSUE(ck, buf) do {                                                  \
        gload_lds16(p_one + (ck) * 32, &one_q[buf][w * 64]);                     \
        _Pragma("unroll")                                                        \
        for (int q = 0; q < 4; ++q)                                              \
            gload_lds16(p_two[q] + (ck) * 32, &two_q[buf][(w * 4 + q) * 64]);    \
    } while (0)

    // raw barrier: drain own LDS ops, do NOT drain vmcnt (DMA stays in flight)
    #define BAR() asm volatile("s_waitcnt lgkmcnt(0)\n\ts_barrier" ::: "memory")

    floatx4 acc[9][2];
    #pragma unroll
    for (int dy = 0; dy < 9; ++dy) {
        acc[dy][0] = floatx4{0.f, 0.f, 0.f, 0.f};
        acc[dy][1] = floatx4{0.f, 0.f, 0.f, 0.f};
    }

    // ---- prologue: 2 chunks in flight (5 vmem ops each) ----
    ISSUE(0, 0);
    ISSUE(1, 1);

    #pragma unroll
    for (int ck = 0; ck < 4; ++ck) {
        const int cur = ck & 1;
        if (ck < 3) asm volatile("s_waitcnt vmcnt(5)" ::: "memory");
        else        asm volatile("s_waitcnt vmcnt(0)" ::: "memory");
        BAR();   // all waves' DMAs for chunk ck have landed -> safe to read

        const short8 A = *reinterpret_cast<const short8*>(&one_q[cur][w * 64 + lane]);
        #pragma unroll
        for (int dy = 0; dy < 9; ++dy) {
            const int ry = w + dy;
            const short8 Bt0 = *reinterpret_cast<const short8*>(&two_q[cur][ry * 128 + lane]);
            const short8 Bt1 = *reinterpret_cast<const short8*>(&two_q[cur][ry * 128 + 64 + lane]);
            acc[dy][0] = __builtin_amdgcn_mfma_f32_16x16x32_bf16(A, Bt0, acc[dy][0], 0, 0, 0);
            acc[dy][1] = __builtin_amdgcn_mfma_f32_16x16x32_bf16(A, Bt1, acc[dy][1], 0, 0, 0);
        }
        BAR();   // all reads of buf[cur] complete before anyone refills it

        if (ck < 2) ISSUE(ck + 2, cur);
    }

    // ---- epilogue: stage into LDS (overlaid on dead two_q), store coalesced ----
    __syncthreads();                               // everyone done with two_q
    float* ep = reinterpret_cast<float*>(&two_q[0][0]);   // 81*130*4 = 42 KB < 64 KB
    const float scale = 1.0f / (float)C_;
    #pragma unroll
    for (int dy = 0; dy < 9; ++dy) {
        #pragma unroll
        for (int ct = 0; ct < 2; ++ct) {
            floatx4 v = acc[dy][ct];
            #pragma unroll
            for (int r = 0; r < 4; ++r) {
                const int m  = kq * 4 + r;
                const int dx = nn - m + ct * 16;
                if ((unsigned)dx <= 8u)
                    ep[(dy * 9 + dx) * 130 + w * 16 + m] = v[r] * scale;
            }
        }
    }
    __syncthreads();
    // 81 planes * 128 floats = 10368 dwords; lanes cover x fastest -> full 64B lines
    #pragma unroll
    for (int i = 0; i < 21; ++i) {
        const int g = tid + i * 512;
        if (g < 81 * 128) {
            const int p   = g >> 7;
            const int loc = g & 127;               // yy*16 + xx
            const int yy  = loc >> 4, xx = loc & 15;
            out[((size_t)(b * 81 + p) * H_ + y0 + yy) * W_ + x0 + xx] = ep[p * 130 + loc];
        }
    }
    #undef ISSUE
    #undef BAR
}

// ---------------------------------------------------------------------------
// Fallback: harness-verified single-pass kernel (used if workspace too small)
// ---------------------------------------------------------------------------
__global__ __launch_bounds__(512, 2)
void corr_kernel(const float* __restrict__ one, const float* __restrict__ two,
                 float* __restrict__ out) {
    __shared__ uint4 one_q[2][8 * 64];
    __shared__ uint4 two_q[2][16 * 128];

    const int id = blockIdx.x;
    const int b  = id & 7;
    const int jj = id >> 3;
    const int yt = jj % 12;
    const int xt = jj / 12;
    const int y0 = yt * 8;
    const int x0 = xt * 16;

    const int tid  = threadIdx.x;
    const int lane = tid & 63;
    const int w    = tid >> 6;

    const int o_xl  = tid & 15;
    const int o_yl  = (tid >> 4) & 7;
    const int o_kg  = tid >> 7;
    const int o_rec = o_yl * 64 + o_kg * 16 + o_xl;

    const int t_cx  = tid & 31;
    const int t_ry  = tid >> 5;
    const int t_y   = y0 - 4 + t_ry;
    const int t_gx  = x0 - 4 + t_cx;
    const bool t_valid = ((unsigned)t_y < H_) && ((unsigned)t_gx < W_) && (t_cx < 24);
    const int t_rec = t_ry * 128 + (t_cx >> 4) * 64 + (t_cx & 15);

    const float* o_base = one + ((size_t)(b * C_ + 8 * o_kg) * H_ + (y0 + o_yl)) * W_ + (x0 + o_xl);
    const float* t_base = two + ((size_t)(b * C_) * H_ + t_y) * W_ + t_gx;

    float ro[8];
    float rt[32];

    floatx4 acc[9][2];
    #pragma unroll
    for (int dy = 0; dy < 9; ++dy) {
        acc[dy][0] = floatx4{0.f, 0.f, 0.f, 0.f};
        acc[dy][1] = floatx4{0.f, 0.f, 0.f, 0.f};
    }

    {
        const float* p1 = o_base;
        #pragma unroll
        for (int i = 0; i < 8; ++i) ro[i] = p1[(size_t)i * HWp];
        if (t_valid) {
            const float* p2 = t_base;
            #pragma unroll
            for (int i = 0; i < 32; ++i) rt[i] = p2[(size_t)i * HWp];
        } else {
            #pragma unroll
            for (int i = 0; i < 32; ++i) rt[i] = 0.f;
        }
    }

    #pragma unroll
    for (int ck = 0; ck < 4; ++ck) {
        const int bf = ck & 1;
        {
            uint4 v;
            v.x = pk_bf16(ro[0], ro[1]);
            v.y = pk_bf16(ro[2], ro[3]);
            v.z = pk_bf16(ro[4], ro[5]);
            v.w = pk_bf16(ro[6], ro[7]);
            one_q[bf][o_rec] = v;
            #pragma unroll
            for (int kg = 0; kg < 4; ++kg) {
                uint4 u;
                u.x = pk_bf16(rt[kg * 8 + 0], rt[kg * 8 + 1]);
                u.y = pk_bf16(rt[kg * 8 + 2], rt[kg * 8 + 3]);
                u.z = pk_bf16(rt[kg * 8 + 4], rt[kg * 8 + 5]);
                u.w = pk_bf16(rt[kg * 8 + 6], rt[kg * 8 + 7]);
                two_q[bf][t_rec + kg * 16] = u;
            }
        }
        __syncthreads();

        if (ck < 3) {
            const float* p1 = o_base + (size_t)((ck + 1) * 32) * HWp;
            #pragma unroll
            for (int i = 0; i < 8; ++i) ro[i] = p1[(size_t)i * HWp];
            if (t_valid) {
                const float* p2 = t_base + (size_t)((ck + 1) * 32) * HWp;
                #pragma unroll
                for (int i = 0; i < 32; ++i) rt[i] = p2[(size_t)i * HWp];
            }
        }

        const short8 A = *reinterpret_cast<const short8*>(&one_q[bf][w * 64 + lane]);
        #pragma unroll
        for (int dy = 0; dy < 9; ++dy) {
            const int ry = w + dy;
            const short8 Bt0 = *reinterpret_cast<const short8*>(&two_q[bf][ry * 128 + lane]);
            const short8 Bt1 = *reinterpret_cast<const short8*>(&two_q[bf][ry * 128 + 64 + lane]);
            acc[dy][0] = __builtin_amdgcn_mfma_f32_16x16x32_bf16(A, Bt0, acc[dy][0], 0, 0, 0);
            acc[dy][1] = __builtin_amdgcn_mfma_f32_16x16x32_bf16(A, Bt1, acc[dy][1], 0, 0, 0);
        }
    }

    const int  qq = lane >> 4;
    const int  nn2 = lane & 15;
    const int  y  = y0 + w;
    const float scale = 1.0f / (float)C_;
    #pragma unroll
    for (int dy = 0; dy < 9; ++dy) {
        #pragma unroll
        for (int ct = 0; ct < 2; ++ct) {
            floatx4 v = acc[dy][ct];
            #pragma unroll
            for (int r = 0; r < 4; ++r) {
                int m  = qq * 4 + r;
                int dx = nn2 - m + ct * 16;
                if ((unsigned)dx <= 8u) {
                    size_t o = ((size_t)(b * 81 + dy * 9 + dx) * H_ + y) * W_ + (x0 + m);
                    out[o] = v[r] * scale;
                }
            }
        }
    }
}

extern "C" void kernel_launch(void* const* d_in, const int* in_sizes, int n_in,
                              void* d_out, int out_size, void* d_ws, size_t ws_size,
                              hipStream_t stream) {
    const float* one = (const float*)d_in[0];
    const float* two = (const float*)d_in[1];
    float* out = (float*)d_out;
    const size_t need_two = (size_t)B_ * HP * WP * C_ * 2;            // 37,486,592 B
    const size_t need_one = (size_t)B_ * H_ * W_ * C_ * 2;            // 31,457,280 B
    if (d_ws != nullptr && ws_size >= need_two + need_one) {
        unsigned short* two_t = (unsigned short*)d_ws;
        unsigned short* one_t = two_t + (size_t)B_ * HP * WP * C_;
        // prep: 3328 two-blocks + 3072 one-blocks, 256 threads each
        prep_kernel<<<dim3(6400), dim3(256), 0, stream>>>(two, one, two_t, one_t);
        // corr2: 8 batches * 12 y-tiles * 10 x-tiles = 960 blocks
        corr2_kernel<<<dim3(960), dim3(512), 0, stream>>>(one_t, two_t, out);
    } else {
        corr_kernel<<<dim3(960), dim3(512), 0, stream>>>(one, two, out);
    }
}

// Round 10
// 195.588 us; speedup vs baseline: 1.2126x; 1.0239x over previous
//
#include <hip/hip_runtime.h>

#define B_  8
#define C_  128
#define H_  96
#define W_  160
#define HWp (H_ * W_)   // 15360 = one channel plane
#define PADY 4
#define HP  104         // H_ + 2*PADY
#define WP  176         // W_ + 16: halo (+8) plus slack so the 32-wide DMA window never goes OOB

typedef short  short8  __attribute__((ext_vector_type(8)));
typedef float  floatx4 __attribute__((ext_vector_type(4)));

// round-to-nearest-even fp32 -> bf16, packed pair (a low 16, b high 16)
__device__ __forceinline__ unsigned pk_bf16(float a, float b) {
    unsigned ua = __float_as_uint(a);
    unsigned ub = __float_as_uint(b);
    ua = (ua + 0x7FFFu + ((ua >> 16) & 1u)) >> 16;
    ub = (ub + 0x7FFFu + ((ub >> 16) & 1u)) & 0xFFFF0000u;
    return ua | ub;
}

// async 16B-per-lane global->LDS DMA (offset arg must be a literal constant,
// so chunk offsets are folded into the global pointer at the call site).
__device__ __forceinline__ void gload_lds16(const void* g, void* l) {
    __builtin_amdgcn_global_load_lds(
        (const __attribute__((address_space(1))) unsigned int*)g,
        (__attribute__((address_space(3))) unsigned int*)l, 16, 0, 0);
}

// ---------------------------------------------------------------------------
// Prep v7: fp32 NCHW -> bf16 NHWC. v6's conflict-free stride-33 LDS turn
// + v1's 128B write granule (the empirical write law: 16B granule -> 1.53x
// WRITE amplification, 64B -> 1.27x, 128B -> 1.00x).
// Block = (b, row, c-HALF): thread (cp 0..31, q 0..7) loads channels
// 2cp/2cp+1 (10 float4 in flight, v1-proven), packs bf16 pairs in-register,
// LDS [x 160][cp 32] packed words stride 33:
//   - pack-write bank (4q+cp+k)%32  ~2-way  (free per m136)
//   - store-read bank (xs+4part+j)%32 ~2-way (free)
// Store: 8 consecutive lanes = parts 0..7 of ONE record-half = 128B
// contiguous -> zero amplification. 21KB LDS, 256 thr -> 7 blocks/CU.
//   id < 1664 : two rows (b,ypad,ch) -> two_t (border rows zero-fill)
//   id >=1664 : one rows (b,y,ch)    -> one_t
// ---------------------------------------------------------------------------
__global__ __launch_bounds__(256, 7)
void prep_kernel(const float* __restrict__ two, const float* __restrict__ one,
                 unsigned short* __restrict__ two_t,
                 unsigned short* __restrict__ one_t) {
    __shared__ unsigned lds[160 * 33];     // 21,120 B packed bf16-pair words

    const int id  = blockIdx.x;
    const int tid = threadIdx.x;

    if (id < 1664) {
        // ----- two path: (b, ypad, c-half) -----
        const int b    = id & 7;           // batch spread across XCDs
        const int r    = id >> 3;          // 0..207
        const int ypad = r % HP;           // 0..103
        const int ch   = r / HP;           // 0..1
        unsigned short* dstrow = two_t + (size_t)(b * HP + ypad) * WP * C_ + ch * 64;

        if (ypad < PADY || ypad >= PADY + H_) {        // border rows: zeros
            const uint4 z{0u, 0u, 0u, 0u};
            #pragma unroll
            for (int i = 0; i < 6; ++i) {
                const int g = tid + i * 256;           // unit = 16B part of 128B half
                if (g < WP * 8) {
                    const int xp = g >> 3, part = g & 7;
                    *reinterpret_cast<uint4*>(dstrow + (size_t)xp * C_ + part * 8) = z;
                }
            }
            return;
        }

        const int y  = ypad - PADY;
        const int cp = tid >> 3;           // 0..31 channel pair within half
        const int q  = tid & 7;            // x-quad slot
        const float* src = two + ((size_t)(b * C_ + ch * 64 + 2 * cp) * H_ + y) * W_;
        #pragma unroll
        for (int j = 0; j < 5; ++j) {      // 10 float4 in flight (2 ch x 5 quads)
            const int x0 = (j * 8 + q) * 4;
            const floatx4 va = *reinterpret_cast<const floatx4*>(&src[x0]);
            const floatx4 vb = *reinterpret_cast<const floatx4*>(&src[HWp + x0]);
            lds[(x0 + 0) * 33 + cp] = pk_bf16(va[0], vb[0]);
            lds[(x0 + 1) * 33 + cp] = pk_bf16(va[1], vb[1]);
            lds[(x0 + 2) * 33 + cp] = pk_bf16(va[2], vb[2]);
            lds[(x0 + 3) * 33 + cp] = pk_bf16(va[3], vb[3]);
        }
        __syncthreads();
        #pragma unroll
        for (int i = 0; i < 6; ++i) {
            const int g = tid + i * 256;
            if (g < WP * 8) {
                const int xp = g >> 3, part = g & 7;
                const int xs = xp - 4;
                uint4 v{0u, 0u, 0u, 0u};
                if ((unsigned)xs < (unsigned)W_) {
                    const unsigned* p = &lds[xs * 33 + part * 4];
                    v.x = p[0]; v.y = p[1]; v.z = p[2]; v.w = p[3];
                }
                // 8 consecutive lanes (parts 0..7, same xp) fill one 128B half
                *reinterpret_cast<uint4*>(dstrow + (size_t)xp * C_ + part * 8) = v;
            }
        }
    } else {
        // ----- one path: (b, y, c-half), no padding -----
        const int id2 = id - 1664;
        const int b   = id2 & 7;
        const int r   = id2 >> 3;          // 0..191
        const int y   = r % H_;
        const int ch  = r / H_;
        unsigned short* dstrow = one_t + (size_t)(b * H_ + y) * W_ * C_ + ch * 64;

        const int cp = tid >> 3;
        const int q  = tid & 7;
        const float* src = one + ((size_t)(b * C_ + ch * 64 + 2 * cp) * H_ + y) * W_;
        #pragma unroll
        for (int j = 0; j < 5; ++j) {
            const int x0 = (j * 8 + q) * 4;
            const floatx4 va = *reinterpret_cast<const floatx4*>(&src[x0]);
            const floatx4 vb = *reinterpret_cast<const floatx4*>(&src[HWp + x0]);
            lds[(x0 + 0) * 33 + cp] = pk_bf16(va[0], vb[0]);
            lds[(x0 + 1) * 33 + cp] = pk_bf16(va[1], vb[1]);
            lds[(x0 + 2) * 33 + cp] = pk_bf16(va[2], vb[2]);
            lds[(x0 + 3) * 33 + cp] = pk_bf16(va[3], vb[3]);
        }
        __syncthreads();
        #pragma unroll
        for (int i = 0; i < 5; ++i) {      // 160*8 = 1280 units = 5*256 exact
            const int g = tid + i * 256;
            const int x = g >> 3, part = g & 7;
            const unsigned* p = &lds[x * 33 + part * 4];
            uint4 v;
            v.x = p[0]; v.y = p[1]; v.z = p[2]; v.w = p[3];
            *reinterpret_cast<uint4*>(dstrow + (size_t)x * C_ + part * 8) = v;
        }
    }
}

// ---------------------------------------------------------------------------
// Pass 2: band-GEMM correlation, pure-DMA staging (both operands via
// global_load_lds from bf16 NHWC), counted vmcnt, raw barriers, coalesced
// LDS-staged epilogue. (unchanged — harness-verified, ~30 µs)
// ---------------------------------------------------------------------------
__global__ __launch_bounds__(512, 4)
void corr2_kernel(const unsigned short* __restrict__ one_t,
                  const unsigned short* __restrict__ two_t,
                  float* __restrict__ out) {
    __shared__ uint4 two_q[2][16 * 128];   // 32 KB x2: [ry16][ct2*64 + kg4*16 + n16]
    __shared__ uint4 one_q[2][8 * 64];     //  8 KB x2: [y8][kg4*16 + x16]  -> 80 KB total

    const int id = blockIdx.x;
    const int b  = id & 7;            // one batch per XCD
    const int jj = id >> 3;           // 0..119
    const int yt = jj % 12;
    const int xt = jj / 12;
    const int y0 = yt * 8;
    const int x0 = xt * 16;

    const int tid  = threadIdx.x;
    const int lane = tid & 63;
    const int w    = tid >> 6;        // wave id = y-row within tile
    const int kq   = lane >> 4;       // 0..3
    const int nn   = lane & 15;

    // ---- DMA source pointers (per-lane) ----
    const unsigned short* p_one =
        one_t + ((size_t)((b * H_ + y0 + w) * W_ + x0 + nn)) * C_ + kq * 8;
    const unsigned short* p_two[4];
    #pragma unroll
    for (int q = 0; q < 4; ++q) {
        const int ii = w * 4 + q;
        const int ry = ii >> 1, ct = ii & 1;
        p_two[q] = two_t + ((size_t)((b * HP + y0 + ry) * WP + x0 + ct * 16 + nn)) * C_ + kq * 8;
    }

    #define ISSUE(ck, buf) do {                                                  \
        gload_lds16(p_one + (ck) * 32, &one_q[buf][w * 64]);                     \
        _Pragma("unroll")                                                        \
        for (int q = 0; q < 4; ++q)                                              \
            gload_lds16(p_two[q] + (ck) * 32, &two_q[buf][(w * 4 + q) * 64]);    \
    } while (0)

    // raw barrier: drain own LDS ops, do NOT drain vmcnt (DMA stays in flight)
    #define BAR() asm volatile("s_waitcnt lgkmcnt(0)\n\ts_barrier" ::: "memory")

    floatx4 acc[9][2];
    #pragma unroll
    for (int dy = 0; dy < 9; ++dy) {
        acc[dy][0] = floatx4{0.f, 0.f, 0.f, 0.f};
        acc[dy][1] = floatx4{0.f, 0.f, 0.f, 0.f};
    }

    // ---- prologue: 2 chunks in flight (5 vmem ops each) ----
    ISSUE(0, 0);
    ISSUE(1, 1);

    #pragma unroll
    for (int ck = 0; ck < 4; ++ck) {
        const int cur = ck & 1;
        if (ck < 3) asm volatile("s_waitcnt vmcnt(5)" ::: "memory");
        else        asm volatile("s_waitcnt vmcnt(0)" ::: "memory");
        BAR();   // all waves' DMAs for chunk ck have landed -> safe to read

        const short8 A = *reinterpret_cast<const short8*>(&one_q[cur][w * 64 + lane]);
        #pragma unroll
        for (int dy = 0; dy < 9; ++dy) {
            const int ry = w + dy;
            const short8 Bt0 = *reinterpret_cast<const short8*>(&two_q[cur][ry * 128 + lane]);
            const short8 Bt1 = *reinterpret_cast<const short8*>(&two_q[cur][ry * 128 + 64 + lane]);
            acc[dy][0] = __builtin_amdgcn_mfma_f32_16x16x32_bf16(A, Bt0, acc[dy][0], 0, 0, 0);
            acc[dy][1] = __builtin_amdgcn_mfma_f32_16x16x32_bf16(A, Bt1, acc[dy][1], 0, 0, 0);
        }
        BAR();   // all reads of buf[cur] complete before anyone refills it

        if (ck < 2) ISSUE(ck + 2, cur);
    }

    // ---- epilogue: stage into LDS (overlaid on dead two_q), store coalesced ----
    __syncthreads();                               // everyone done with two_q
    float* ep = reinterpret_cast<float*>(&two_q[0][0]);   // 81*130*4 = 42 KB < 64 KB
    const float scale = 1.0f / (float)C_;
    #pragma unroll
    for (int dy = 0; dy < 9; ++dy) {
        #pragma unroll
        for (int ct = 0; ct < 2; ++ct) {
            floatx4 v = acc[dy][ct];
            #pragma unroll
            for (int r = 0; r < 4; ++r) {
                const int m  = kq * 4 + r;
                const int dx = nn - m + ct * 16;
                if ((unsigned)dx <= 8u)
                    ep[(dy * 9 + dx) * 130 + w * 16 + m] = v[r] * scale;
            }
        }
    }
    __syncthreads();
    // 81 planes * 128 floats = 10368 dwords; lanes cover x fastest -> full 64B lines
    #pragma unroll
    for (int i = 0; i < 21; ++i) {
        const int g = tid + i * 512;
        if (g < 81 * 128) {
            const int p   = g >> 7;
            const int loc = g & 127;               // yy*16 + xx
            const int yy  = loc >> 4, xx = loc & 15;
            out[((size_t)(b * 81 + p) * H_ + y0 + yy) * W_ + x0 + xx] = ep[p * 130 + loc];
        }
    }
    #undef ISSUE
    #undef BAR
}

// ---------------------------------------------------------------------------
// Fallback: harness-verified single-pass kernel (used if workspace too small)
// ---------------------------------------------------------------------------
__global__ __launch_bounds__(512, 2)
void corr_kernel(const float* __restrict__ one, const float* __restrict__ two,
                 float* __restrict__ out) {
    __shared__ uint4 one_q[2][8 * 64];
    __shared__ uint4 two_q[2][16 * 128];

    const int id = blockIdx.x;
    const int b  = id & 7;
    const int jj = id >> 3;
    const int yt = jj % 12;
    const int xt = jj / 12;
    const int y0 = yt * 8;
    const int x0 = xt * 16;

    const int tid  = threadIdx.x;
    const int lane = tid & 63;
    const int w    = tid >> 6;

    const int o_xl  = tid & 15;
    const int o_yl  = (tid >> 4) & 7;
    const int o_kg  = tid >> 7;
    const int o_rec = o_yl * 64 + o_kg * 16 + o_xl;

    const int t_cx  = tid & 31;
    const int t_ry  = tid >> 5;
    const int t_y   = y0 - 4 + t_ry;
    const int t_gx  = x0 - 4 + t_cx;
    const bool t_valid = ((unsigned)t_y < H_) && ((unsigned)t_gx < W_) && (t_cx < 24);
    const int t_rec = t_ry * 128 + (t_cx >> 4) * 64 + (t_cx & 15);

    const float* o_base = one + ((size_t)(b * C_ + 8 * o_kg) * H_ + (y0 + o_yl)) * W_ + (x0 + o_xl);
    const float* t_base = two + ((size_t)(b * C_) * H_ + t_y) * W_ + t_gx;

    float ro[8];
    float rt[32];

    floatx4 acc[9][2];
    #pragma unroll
    for (int dy = 0; dy < 9; ++dy) {
        acc[dy][0] = floatx4{0.f, 0.f, 0.f, 0.f};
        acc[dy][1] = floatx4{0.f, 0.f, 0.f, 0.f};
    }

    {
        const float* p1 = o_base;
        #pragma unroll
        for (int i = 0; i < 8; ++i) ro[i] = p1[(size_t)i * HWp];
        if (t_valid) {
            const float* p2 = t_base;
            #pragma unroll
            for (int i = 0; i < 32; ++i) rt[i] = p2[(size_t)i * HWp];
        } else {
            #pragma unroll
            for (int i = 0; i < 32; ++i) rt[i] = 0.f;
        }
    }

    #pragma unroll
    for (int ck = 0; ck < 4; ++ck) {
        const int bf = ck & 1;
        {
            uint4 v;
            v.x = pk_bf16(ro[0], ro[1]);
            v.y = pk_bf16(ro[2], ro[3]);
            v.z = pk_bf16(ro[4], ro[5]);
            v.w = pk_bf16(ro[6], ro[7]);
            one_q[bf][o_rec] = v;
            #pragma unroll
            for (int kg = 0; kg < 4; ++kg) {
                uint4 u;
                u.x = pk_bf16(rt[kg * 8 + 0], rt[kg * 8 + 1]);
                u.y = pk_bf16(rt[kg * 8 + 2], rt[kg * 8 + 3]);
                u.z = pk_bf16(rt[kg * 8 + 4], rt[kg * 8 + 5]);
                u.w = pk_bf16(rt[kg * 8 + 6], rt[kg * 8 + 7]);
                two_q[bf][t_rec + kg * 16] = u;
            }
        }
        __syncthreads();

        if (ck < 3) {
            const float* p1 = o_base + (size_t)((ck + 1) * 32) * HWp;
            #pragma unroll
            for (int i = 0; i < 8; ++i) ro[i] = p1[(size_t)i * HWp];
            if (t_valid) {
                const float* p2 = t_base + (size_t)((ck + 1) * 32) * HWp;
                #pragma unroll
                for (int i = 0; i < 32; ++i) rt[i] = p2[(size_t)i * HWp];
            }
        }

        const short8 A = *reinterpret_cast<const short8*>(&one_q[bf][w * 64 + lane]);
        #pragma unroll
        for (int dy = 0; dy < 9; ++dy) {
            const int ry = w + dy;
            const short8 Bt0 = *reinterpret_cast<const short8*>(&two_q[bf][ry * 128 + lane]);
            const short8 Bt1 = *reinterpret_cast<const short8*>(&two_q[bf][ry * 128 + 64 + lane]);
            acc[dy][0] = __builtin_amdgcn_mfma_f32_16x16x32_bf16(A, Bt0, acc[dy][0], 0, 0, 0);
            acc[dy][1] = __builtin_amdgcn_mfma_f32_16x16x32_bf16(A, Bt1, acc[dy][1], 0, 0, 0);
        }
    }

    const int  qq = lane >> 4;
    const int  nn2 = lane & 15;
    const int  y  = y0 + w;
    const float scale = 1.0f / (float)C_;
    #pragma unroll
    for (int dy = 0; dy < 9; ++dy) {
        #pragma unroll
        for (int ct = 0; ct < 2; ++ct) {
            floatx4 v = acc[dy][ct];
            #pragma unroll
            for (int r = 0; r < 4; ++r) {
                int m  = qq * 4 + r;
                int dx = nn2 - m + ct * 16;
                if ((unsigned)dx <= 8u) {
                    size_t o = ((size_t)(b * 81 + dy * 9 + dx) * H_ + y) * W_ + (x0 + m);
                    out[o] = v[r] * scale;
                }
            }
        }
    }
}

extern "C" void kernel_launch(void* const* d_in, const int* in_sizes, int n_in,
                              void* d_out, int out_size, void* d_ws, size_t ws_size,
                              hipStream_t stream) {
    const float* one = (const float*)d_in[0];
    const float* two = (const float*)d_in[1];
    float* out = (float*)d_out;
    const size_t need_two = (size_t)B_ * HP * WP * C_ * 2;            // 37,486,592 B
    const size_t need_one = (size_t)B_ * H_ * W_ * C_ * 2;            // 31,457,280 B
    if (d_ws != nullptr && ws_size >= need_two + need_one) {
        unsigned short* two_t = (unsigned short*)d_ws;
        unsigned short* one_t = two_t + (size_t)B_ * HP * WP * C_;
        // prep: 1664 two-blocks + 1536 one-blocks, 256 threads each
        prep_kernel<<<dim3(3200), dim3(256), 0, stream>>>(two, one, two_t, one_t);
        // corr2: 8 batches * 12 y-tiles * 10 x-tiles = 960 blocks
        corr2_kernel<<<dim3(960), dim3(512), 0, stream>>>(one_t, two_t, out);
    } else {
        corr_kernel<<<dim3(960), dim3(512), 0, stream>>>(one, two, out);
    }
}

// Round 11
// 188.743 us; speedup vs baseline: 1.2565x; 1.0363x over previous
//
#include <hip/hip_runtime.h>

#define B_  8
#define C_  128
#define H_  96
#define W_  160
#define HWp (H_ * W_)   // 15360 = one channel plane (floats / pair-words)

typedef short  short8  __attribute__((ext_vector_type(8)));
typedef float  floatx4 __attribute__((ext_vector_type(4)));

// round-to-nearest-even fp32 -> bf16, packed pair (a low 16, b high 16)
__device__ __forceinline__ unsigned pk_bf16(float a, float b) {
    unsigned ua = __float_as_uint(a);
    unsigned ub = __float_as_uint(b);
    ua = (ua + 0x7FFFu + ((ua >> 16) & 1u)) >> 16;
    ub = (ub + 0x7FFFu + ((ub >> 16) & 1u)) & 0xFFFF0000u;
    return ua | ub;
}

// ---------------------------------------------------------------------------
// Prep v8: fp32 NCHW -> channel-paired bf16 NCHW, PURE STREAMING (no
// transpose). 7 transpose variants all capped at ~2.1 TB/s (the gather/
// scatter shape is the floor on this chip) — so the corner turn is deleted:
//   out_p[b][cp][y][x] = pack(in[b][2cp][y][x], in[b][2cp+1][y][x])
// Reads = 2 sequential plane streams, write = 1 sequential stream, 1KB per
// wave instruction on all three. Channel-adjacency for MFMA records is then
// free in corr3's existing LDS staging (1 b32 = 2 channels).
//   id < 2560 : two -> two_p     id >= 2560 : one -> one_p
// block = (b, cp, seg of 3072 floats); 384 thr x 2 float4-units each.
// ---------------------------------------------------------------------------
__global__ __launch_bounds__(384, 4)
void prep_convert(const float* __restrict__ two, const float* __restrict__ one,
                  unsigned* __restrict__ two_p, unsigned* __restrict__ one_p) {
    const int id  = blockIdx.x;
    const int tid = threadIdx.x;
    const bool istwo = id < 2560;
    const int id2 = istwo ? id : id - 2560;
    const int b   = id2 & 7;            // batch spread across XCDs
    const int r   = id2 >> 3;           // 0..319
    const int cp  = r & 63;             // channel pair
    const int seg = r >> 6;             // 0..4, 3072-float span

    const float* s0 = (istwo ? two : one) + ((size_t)(b * C_ + 2 * cp)) * HWp + seg * 3072;
    const float* s1 = s0 + HWp;
    unsigned*    d  = (istwo ? two_p : one_p) + ((size_t)(b * 64 + cp)) * HWp + seg * 3072;

    #pragma unroll
    for (int i = 0; i < 2; ++i) {
        const int u = tid + i * 384;    // float4-unit 0..767
        const floatx4 a = *reinterpret_cast<const floatx4*>(s0 + u * 4);
        const floatx4 c = *reinterpret_cast<const floatx4*>(s1 + u * 4);
        uint4 v;
        v.x = pk_bf16(a[0], c[0]);
        v.y = pk_bf16(a[1], c[1]);
        v.z = pk_bf16(a[2], c[2]);
        v.w = pk_bf16(a[3], c[3]);
        *reinterpret_cast<uint4*>(d + u * 4) = v;
    }
}

// ---------------------------------------------------------------------------
// corr3: band-GEMM correlation on channel-paired bf16. Same proven staging
// map as the original harness-verified corr_kernel, but loads are u32
// (2 channels each: 16+4 per thread per chunk vs 40 fp32) and the commit is
// a pure register->LDS move (no pk_bf16 VALU). Halo via t_valid predication
// (no padded tensor). Epilogue = proven LDS-staged coalesced store.
// ---------------------------------------------------------------------------
__global__ __launch_bounds__(512, 2)
void corr3_kernel(const unsigned* __restrict__ one_p, const unsigned* __restrict__ two_p,
                  float* __restrict__ out) {
    __shared__ uint4 one_q[2][8 * 64];     //  8 KB x2
    __shared__ uint4 two_q[2][16 * 128];   // 32 KB x2 -> 80 KB total

    const int id = blockIdx.x;
    const int b  = id & 7;            // one batch per XCD
    const int jj = id >> 3;           // 0..119
    const int yt = jj % 12;
    const int xt = jj / 12;
    const int y0 = yt * 8;
    const int x0 = xt * 16;

    const int tid  = threadIdx.x;
    const int lane = tid & 63;
    const int w    = tid >> 6;        // wave id = y-row within tile
    const int kq   = lane >> 4;       // 0..3
    const int nn   = lane & 15;

    // `one` staging: thread -> (x16, y8, kg4); one 16B record (4 pair-words)
    const int o_xl  = tid & 15;
    const int o_yl  = (tid >> 4) & 7;
    const int o_kg  = tid >> 7;
    const int o_rec = o_yl * 64 + o_kg * 16 + o_xl;

    // `two` staging: thread -> (cx32, ry16); 4 records (16 pair-words)
    const int t_cx  = tid & 31;
    const int t_ry  = tid >> 5;
    const int t_y   = y0 - 4 + t_ry;
    const int t_gx  = x0 - 4 + t_cx;
    const bool t_valid = ((unsigned)t_y < H_) && ((unsigned)t_gx < W_) && (t_cx < 24);
    const int t_rec = t_ry * 128 + (t_cx >> 4) * 64 + (t_cx & 15);

    const unsigned* o_base = one_p + ((size_t)(b * 64 + 4 * o_kg) * H_ + (y0 + o_yl)) * W_ + (x0 + o_xl);
    const unsigned* t_base = two_p + ((size_t)(b * 64) * H_ + t_y) * W_ + t_gx;

    unsigned ro[4];    // 4 pair-words = 8 consecutive c at (x,y)
    unsigned rt[16];   // 16 pair-words = 32 consecutive c at (x2,ry)

    floatx4 acc[9][2];
    #pragma unroll
    for (int dy = 0; dy < 9; ++dy) {
        acc[dy][0] = floatx4{0.f, 0.f, 0.f, 0.f};
        acc[dy][1] = floatx4{0.f, 0.f, 0.f, 0.f};
    }

    // ---- issue loads for chunk 0 ----
    {
        #pragma unroll
        for (int i = 0; i < 4; ++i) ro[i] = o_base[(size_t)i * HWp];
        if (t_valid) {
            #pragma unroll
            for (int i = 0; i < 16; ++i) rt[i] = t_base[(size_t)i * HWp];
        } else {
            #pragma unroll
            for (int i = 0; i < 16; ++i) rt[i] = 0u;
        }
    }

    #pragma unroll
    for (int ck = 0; ck < 4; ++ck) {
        const int bf = ck & 1;

        // ---- commit chunk ck (pure register->LDS, no pack VALU) ----
        one_q[bf][o_rec] = uint4{ro[0], ro[1], ro[2], ro[3]};
        #pragma unroll
        for (int kg = 0; kg < 4; ++kg)
            two_q[bf][t_rec + kg * 16] = uint4{rt[kg*4+0], rt[kg*4+1], rt[kg*4+2], rt[kg*4+3]};
        __syncthreads();
        // Single barrier per chunk is safe: next commit targets the OTHER
        // buffer, and no wave can get 2 chunks ahead.

        // ---- issue loads for chunk ck+1 (overlap with MFMAs below) ----
        if (ck < 3) {
            const unsigned* p1 = o_base + (size_t)((ck + 1) * 16) * HWp;
            #pragma unroll
            for (int i = 0; i < 4; ++i) ro[i] = p1[(size_t)i * HWp];
            if (t_valid) {
                const unsigned* p2 = t_base + (size_t)((ck + 1) * 16) * HWp;
                #pragma unroll
                for (int i = 0; i < 16; ++i) rt[i] = p2[(size_t)i * HWp];
            }
        }

        // ---- band MFMAs: wave w = y-row, 9 dy x 2 col-tiles ----
        const short8 A = *reinterpret_cast<const short8*>(&one_q[bf][w * 64 + lane]);
        #pragma unroll
        for (int dy = 0; dy < 9; ++dy) {
            const int ry = w + dy;
            const short8 Bt0 = *reinterpret_cast<const short8*>(&two_q[bf][ry * 128 + lane]);
            const short8 Bt1 = *reinterpret_cast<const short8*>(&two_q[bf][ry * 128 + 64 + lane]);
            acc[dy][0] = __builtin_amdgcn_mfma_f32_16x16x32_bf16(A, Bt0, acc[dy][0], 0, 0, 0);
            acc[dy][1] = __builtin_amdgcn_mfma_f32_16x16x32_bf16(A, Bt1, acc[dy][1], 0, 0, 0);
        }
    }

    // ---- epilogue: stage into LDS (overlaid on dead two_q), store coalesced ----
    __syncthreads();                               // everyone done with two_q
    float* ep = reinterpret_cast<float*>(&two_q[0][0]);   // 81*130*4 = 42 KB < 64 KB
    const float scale = 1.0f / (float)C_;
    #pragma unroll
    for (int dy = 0; dy < 9; ++dy) {
        #pragma unroll
        for (int ct = 0; ct < 2; ++ct) {
            floatx4 v = acc[dy][ct];
            #pragma unroll
            for (int r = 0; r < 4; ++r) {
                const int m  = kq * 4 + r;
                const int dx = nn - m + ct * 16;
                if ((unsigned)dx <= 8u)
                    ep[(dy * 9 + dx) * 130 + w * 16 + m] = v[r] * scale;
            }
        }
    }
    __syncthreads();
    // 81 planes * 128 floats; lanes cover x fastest -> full 64B lines
    #pragma unroll
    for (int i = 0; i < 21; ++i) {
        const int g = tid + i * 512;
        if (g < 81 * 128) {
            const int p   = g >> 7;
            const int loc = g & 127;               // yy*16 + xx
            const int yy  = loc >> 4, xx = loc & 15;
            out[((size_t)(b * 81 + p) * H_ + y0 + yy) * W_ + x0 + xx] = ep[p * 130 + loc];
        }
    }
}

// ---------------------------------------------------------------------------
// Fallback: harness-verified single-pass fp32 kernel (used if ws too small)
// ---------------------------------------------------------------------------
__global__ __launch_bounds__(512, 2)
void corr_kernel(const float* __restrict__ one, const float* __restrict__ two,
                 float* __restrict__ out) {
    __shared__ uint4 one_q[2][8 * 64];
    __shared__ uint4 two_q[2][16 * 128];

    const int id = blockIdx.x;
    const int b  = id & 7;
    const int jj = id >> 3;
    const int yt = jj % 12;
    const int xt = jj / 12;
    const int y0 = yt * 8;
    const int x0 = xt * 16;

    const int tid  = threadIdx.x;
    const int lane = tid & 63;
    const int w    = tid >> 6;

    const int o_xl  = tid & 15;
    const int o_yl  = (tid >> 4) & 7;
    const int o_kg  = tid >> 7;
    const int o_rec = o_yl * 64 + o_kg * 16 + o_xl;

    const int t_cx  = tid & 31;
    const int t_ry  = tid >> 5;
    const int t_y   = y0 - 4 + t_ry;
    const int t_gx  = x0 - 4 + t_cx;
    const bool t_valid = ((unsigned)t_y < H_) && ((unsigned)t_gx < W_) && (t_cx < 24);
    const int t_rec = t_ry * 128 + (t_cx >> 4) * 64 + (t_cx & 15);

    const float* o_base = one + ((size_t)(b * C_ + 8 * o_kg) * H_ + (y0 + o_yl)) * W_ + (x0 + o_xl);
    const float* t_base = two + ((size_t)(b * C_) * H_ + t_y) * W_ + t_gx;

    float ro[8];
    float rt[32];

    floatx4 acc[9][2];
    #pragma unroll
    for (int dy = 0; dy < 9; ++dy) {
        acc[dy][0] = floatx4{0.f, 0.f, 0.f, 0.f};
        acc[dy][1] = floatx4{0.f, 0.f, 0.f, 0.f};
    }

    {
        const float* p1 = o_base;
        #pragma unroll
        for (int i = 0; i < 8; ++i) ro[i] = p1[(size_t)i * HWp];
        if (t_valid) {
            const float* p2 = t_base;
            #pragma unroll
            for (int i = 0; i < 32; ++i) rt[i] = p2[(size_t)i * HWp];
        } else {
            #pragma unroll
            for (int i = 0; i < 32; ++i) rt[i] = 0.f;
        }
    }

    #pragma unroll
    for (int ck = 0; ck < 4; ++ck) {
        const int bf = ck & 1;
        {
            uint4 v;
            v.x = pk_bf16(ro[0], ro[1]);
            v.y = pk_bf16(ro[2], ro[3]);
            v.z = pk_bf16(ro[4], ro[5]);
            v.w = pk_bf16(ro[6], ro[7]);
            one_q[bf][o_rec] = v;
            #pragma unroll
            for (int kg = 0; kg < 4; ++kg) {
                uint4 u;
                u.x = pk_bf16(rt[kg * 8 + 0], rt[kg * 8 + 1]);
                u.y = pk_bf16(rt[kg * 8 + 2], rt[kg * 8 + 3]);
                u.z = pk_bf16(rt[kg * 8 + 4], rt[kg * 8 + 5]);
                u.w = pk_bf16(rt[kg * 8 + 6], rt[kg * 8 + 7]);
                two_q[bf][t_rec + kg * 16] = u;
            }
        }
        __syncthreads();

        if (ck < 3) {
            const float* p1 = o_base + (size_t)((ck + 1) * 32) * HWp;
            #pragma unroll
            for (int i = 0; i < 8; ++i) ro[i] = p1[(size_t)i * HWp];
            if (t_valid) {
                const float* p2 = t_base + (size_t)((ck + 1) * 32) * HWp;
                #pragma unroll
                for (int i = 0; i < 32; ++i) rt[i] = p2[(size_t)i * HWp];
            }
        }

        const short8 A = *reinterpret_cast<const short8*>(&one_q[bf][w * 64 + lane]);
        #pragma unroll
        for (int dy = 0; dy < 9; ++dy) {
            const int ry = w + dy;
            const short8 Bt0 = *reinterpret_cast<const short8*>(&two_q[bf][ry * 128 + lane]);
            const short8 Bt1 = *reinterpret_cast<const short8*>(&two_q[bf][ry * 128 + 64 + lane]);
            acc[dy][0] = __builtin_amdgcn_mfma_f32_16x16x32_bf16(A, Bt0, acc[dy][0], 0, 0, 0);
            acc[dy][1] = __builtin_amdgcn_mfma_f32_16x16x32_bf16(A, Bt1, acc[dy][1], 0, 0, 0);
        }
    }

    const int  qq = lane >> 4;
    const int  nn2 = lane & 15;
    const int  y  = y0 + w;
    const float scale = 1.0f / (float)C_;
    #pragma unroll
    for (int dy = 0; dy < 9; ++dy) {
        #pragma unroll
        for (int ct = 0; ct < 2; ++ct) {
            floatx4 v = acc[dy][ct];
            #pragma unroll
            for (int r = 0; r < 4; ++r) {
                int m  = qq * 4 + r;
                int dx = nn2 - m + ct * 16;
                if ((unsigned)dx <= 8u) {
                    size_t o = ((size_t)(b * 81 + dy * 9 + dx) * H_ + y) * W_ + (x0 + m);
                    out[o] = v[r] * scale;
                }
            }
        }
    }
}

extern "C" void kernel_launch(void* const* d_in, const int* in_sizes, int n_in,
                              void* d_out, int out_size, void* d_ws, size_t ws_size,
                              hipStream_t stream) {
    const float* one = (const float*)d_in[0];
    const float* two = (const float*)d_in[1];
    float* out = (float*)d_out;
    const size_t words = (size_t)B_ * 64 * HWp;        // pair-words per tensor
    const size_t need  = 2 * words * 4;                // 62,914,560 B
    if (d_ws != nullptr && ws_size >= need) {
        unsigned* two_p = (unsigned*)d_ws;
        unsigned* one_p = two_p + words;
        // prep: 2560 two-blocks + 2560 one-blocks, 384 threads, pure streaming
        prep_convert<<<dim3(5120), dim3(384), 0, stream>>>(two, one, two_p, one_p);
        // corr3: 8 batches * 12 y-tiles * 10 x-tiles = 960 blocks
        corr3_kernel<<<dim3(960), dim3(512), 0, stream>>>(one_p, two_p, out);
    } else {
        corr_kernel<<<dim3(960), dim3(512), 0, stream>>>(one, two, out);
    }
}

// Round 12
// 187.358 us; speedup vs baseline: 1.2658x; 1.0074x over previous
//
#include <hip/hip_runtime.h>

#define B_  8
#define C_  128
#define H_  96
#define W_  160
#define HWp (H_ * W_)   // 15360 = one channel plane (floats / pair-words)

typedef short  short8  __attribute__((ext_vector_type(8)));
typedef float  floatx4 __attribute__((ext_vector_type(4)));

// round-to-nearest-even fp32 -> bf16, packed pair (a low 16, b high 16)
__device__ __forceinline__ unsigned pk_bf16(float a, float b) {
    unsigned ua = __float_as_uint(a);
    unsigned ub = __float_as_uint(b);
    ua = (ua + 0x7FFFu + ((ua >> 16) & 1u)) >> 16;
    ub = (ub + 0x7FFFu + ((ub >> 16) & 1u)) & 0xFFFF0000u;
    return ua | ub;
}

// ---------------------------------------------------------------------------
// Prep v9: fp32 NCHW -> channel-paired bf16 NCHW, pure streaming, DEEP ILP.
// v8 post-mortem: identical streaming shape ran at 2.08 TB/s with VGPR=16 —
// the compiler held only ~2 loads in flight per wave (Little's law wall),
// while corr3 proved ~2.9 TB/s is reachable. v9 forces the pipeline to
// exist: each thread issues 10 dwordx4 loads (5 units x 2 planes, 40 VGPR
// payload), then a compiler scheduling fence (asm memory clobber) forbids
// sinking them below the pack/store batch. 24 waves/CU x 10KB in flight.
// Block = (b, cp, half-plane): 384 threads x 5 units of 1920.
//   id < 1024 : two -> two_p     id >= 1024 : one -> one_p
// ---------------------------------------------------------------------------
__global__ __launch_bounds__(384, 6)
void prep_convert(const float* __restrict__ two, const float* __restrict__ one,
                  unsigned* __restrict__ two_p, unsigned* __restrict__ one_p) {
    const int id  = blockIdx.x;
    const int tid = threadIdx.x;
    const bool istwo = id < 1024;
    const int id2 = istwo ? id : id - 1024;
    const int b   = id2 & 7;            // batch spread across XCDs
    const int r   = id2 >> 3;           // 0..127
    const int cp  = r & 63;             // channel pair
    const int h   = r >> 6;             // 0..1 half-plane (7680 floats)

    const float* s0 = (istwo ? two : one) + ((size_t)(b * C_ + 2 * cp)) * HWp + h * 7680;
    const float* s1 = s0 + HWp;
    unsigned*    d  = (istwo ? two_p : one_p) + ((size_t)(b * 64 + cp)) * HWp + h * 7680;

    floatx4 a[5], c[5];
    #pragma unroll
    for (int j = 0; j < 5; ++j) {       // 10 dwordx4 issued back-to-back
        const int u = tid + j * 384;    // unit 0..1919; lanes contiguous -> 1KB/instr
        a[j] = *reinterpret_cast<const floatx4*>(s0 + (size_t)u * 4);
        c[j] = *reinterpret_cast<const floatx4*>(s1 + (size_t)u * 4);
    }
    asm volatile("" ::: "memory");      // scheduling fence: loads stay ABOVE stores
    #pragma unroll
    for (int j = 0; j < 5; ++j) {
        const int u = tid + j * 384;
        uint4 v;
        v.x = pk_bf16(a[j][0], c[j][0]);
        v.y = pk_bf16(a[j][1], c[j][1]);
        v.z = pk_bf16(a[j][2], c[j][2]);
        v.w = pk_bf16(a[j][3], c[j][3]);
        *reinterpret_cast<uint4*>(d + (size_t)u * 4) = v;
    }
}

// ---------------------------------------------------------------------------
// corr3: band-GEMM correlation on channel-paired bf16. (unchanged — ~34 µs,
// harness-verified) u32 loads = 2 channels each; commit is a pure
// register->LDS move; halo via t_valid predication; LDS-staged epilogue.
// ---------------------------------------------------------------------------
__global__ __launch_bounds__(512, 2)
void corr3_kernel(const unsigned* __restrict__ one_p, const unsigned* __restrict__ two_p,
                  float* __restrict__ out) {
    __shared__ uint4 one_q[2][8 * 64];     //  8 KB x2
    __shared__ uint4 two_q[2][16 * 128];   // 32 KB x2 -> 80 KB total

    const int id = blockIdx.x;
    const int b  = id & 7;            // one batch per XCD
    const int jj = id >> 3;           // 0..119
    const int yt = jj % 12;
    const int xt = jj / 12;
    const int y0 = yt * 8;
    const int x0 = xt * 16;

    const int tid  = threadIdx.x;
    const int lane = tid & 63;
    const int w    = tid >> 6;        // wave id = y-row within tile
    const int kq   = lane >> 4;       // 0..3
    const int nn   = lane & 15;

    // `one` staging: thread -> (x16, y8, kg4); one 16B record (4 pair-words)
    const int o_xl  = tid & 15;
    const int o_yl  = (tid >> 4) & 7;
    const int o_kg  = tid >> 7;
    const int o_rec = o_yl * 64 + o_kg * 16 + o_xl;

    // `two` staging: thread -> (cx32, ry16); 4 records (16 pair-words)
    const int t_cx  = tid & 31;
    const int t_ry  = tid >> 5;
    const int t_y   = y0 - 4 + t_ry;
    const int t_gx  = x0 - 4 + t_cx;
    const bool t_valid = ((unsigned)t_y < H_) && ((unsigned)t_gx < W_) && (t_cx < 24);
    const int t_rec = t_ry * 128 + (t_cx >> 4) * 64 + (t_cx & 15);

    const unsigned* o_base = one_p + ((size_t)(b * 64 + 4 * o_kg) * H_ + (y0 + o_yl)) * W_ + (x0 + o_xl);
    const unsigned* t_base = two_p + ((size_t)(b * 64) * H_ + t_y) * W_ + t_gx;

    unsigned ro[4];    // 4 pair-words = 8 consecutive c at (x,y)
    unsigned rt[16];   // 16 pair-words = 32 consecutive c at (x2,ry)

    floatx4 acc[9][2];
    #pragma unroll
    for (int dy = 0; dy < 9; ++dy) {
        acc[dy][0] = floatx4{0.f, 0.f, 0.f, 0.f};
        acc[dy][1] = floatx4{0.f, 0.f, 0.f, 0.f};
    }

    // ---- issue loads for chunk 0 ----
    {
        #pragma unroll
        for (int i = 0; i < 4; ++i) ro[i] = o_base[(size_t)i * HWp];
        if (t_valid) {
            #pragma unroll
            for (int i = 0; i < 16; ++i) rt[i] = t_base[(size_t)i * HWp];
        } else {
            #pragma unroll
            for (int i = 0; i < 16; ++i) rt[i] = 0u;
        }
    }

    #pragma unroll
    for (int ck = 0; ck < 4; ++ck) {
        const int bf = ck & 1;

        // ---- commit chunk ck (pure register->LDS, no pack VALU) ----
        one_q[bf][o_rec] = uint4{ro[0], ro[1], ro[2], ro[3]};
        #pragma unroll
        for (int kg = 0; kg < 4; ++kg)
            two_q[bf][t_rec + kg * 16] = uint4{rt[kg*4+0], rt[kg*4+1], rt[kg*4+2], rt[kg*4+3]};
        __syncthreads();
        // Single barrier per chunk is safe: next commit targets the OTHER
        // buffer, and no wave can get 2 chunks ahead.

        // ---- issue loads for chunk ck+1 (overlap with MFMAs below) ----
        if (ck < 3) {
            const unsigned* p1 = o_base + (size_t)((ck + 1) * 16) * HWp;
            #pragma unroll
            for (int i = 0; i < 4; ++i) ro[i] = p1[(size_t)i * HWp];
            if (t_valid) {
                const unsigned* p2 = t_base + (size_t)((ck + 1) * 16) * HWp;
                #pragma unroll
                for (int i = 0; i < 16; ++i) rt[i] = p2[(size_t)i * HWp];
            }
        }

        // ---- band MFMAs: wave w = y-row, 9 dy x 2 col-tiles ----
        const short8 A = *reinterpret_cast<const short8*>(&one_q[bf][w * 64 + lane]);
        #pragma unroll
        for (int dy = 0; dy < 9; ++dy) {
            const int ry = w + dy;
            const short8 Bt0 = *reinterpret_cast<const short8*>(&two_q[bf][ry * 128 + lane]);
            const short8 Bt1 = *reinterpret_cast<const short8*>(&two_q[bf][ry * 128 + 64 + lane]);
            acc[dy][0] = __builtin_amdgcn_mfma_f32_16x16x32_bf16(A, Bt0, acc[dy][0], 0, 0, 0);
            acc[dy][1] = __builtin_amdgcn_mfma_f32_16x16x32_bf16(A, Bt1, acc[dy][1], 0, 0, 0);
        }
    }

    // ---- epilogue: stage into LDS (overlaid on dead two_q), store coalesced ----
    __syncthreads();                               // everyone done with two_q
    float* ep = reinterpret_cast<float*>(&two_q[0][0]);   // 81*130*4 = 42 KB < 64 KB
    const float scale = 1.0f / (float)C_;
    #pragma unroll
    for (int dy = 0; dy < 9; ++dy) {
        #pragma unroll
        for (int ct = 0; ct < 2; ++ct) {
            floatx4 v = acc[dy][ct];
            #pragma unroll
            for (int r = 0; r < 4; ++r) {
                const int m  = kq * 4 + r;
                const int dx = nn - m + ct * 16;
                if ((unsigned)dx <= 8u)
                    ep[(dy * 9 + dx) * 130 + w * 16 + m] = v[r] * scale;
            }
        }
    }
    __syncthreads();
    // 81 planes * 128 floats; lanes cover x fastest -> full 64B lines
    #pragma unroll
    for (int i = 0; i < 21; ++i) {
        const int g = tid + i * 512;
        if (g < 81 * 128) {
            const int p   = g >> 7;
            const int loc = g & 127;               // yy*16 + xx
            const int yy  = loc >> 4, xx = loc & 15;
            out[((size_t)(b * 81 + p) * H_ + y0 + yy) * W_ + x0 + xx] = ep[p * 130 + loc];
        }
    }
}

// ---------------------------------------------------------------------------
// Fallback: harness-verified single-pass fp32 kernel (used if ws too small)
// ---------------------------------------------------------------------------
__global__ __launch_bounds__(512, 2)
void corr_kernel(const float* __restrict__ one, const float* __restrict__ two,
                 float* __restrict__ out) {
    __shared__ uint4 one_q[2][8 * 64];
    __shared__ uint4 two_q[2][16 * 128];

    const int id = blockIdx.x;
    const int b  = id & 7;
    const int jj = id >> 3;
    const int yt = jj % 12;
    const int xt = jj / 12;
    const int y0 = yt * 8;
    const int x0 = xt * 16;

    const int tid  = threadIdx.x;
    const int lane = tid & 63;
    const int w    = tid >> 6;

    const int o_xl  = tid & 15;
    const int o_yl  = (tid >> 4) & 7;
    const int o_kg  = tid >> 7;
    const int o_rec = o_yl * 64 + o_kg * 16 + o_xl;

    const int t_cx  = tid & 31;
    const int t_ry  = tid >> 5;
    const int t_y   = y0 - 4 + t_ry;
    const int t_gx  = x0 - 4 + t_cx;
    const bool t_valid = ((unsigned)t_y < H_) && ((unsigned)t_gx < W_) && (t_cx < 24);
    const int t_rec = t_ry * 128 + (t_cx >> 4) * 64 + (t_cx & 15);

    const float* o_base = one + ((size_t)(b * C_ + 8 * o_kg) * H_ + (y0 + o_yl)) * W_ + (x0 + o_xl);
    const float* t_base = two + ((size_t)(b * C_) * H_ + t_y) * W_ + t_gx;

    float ro[8];
    float rt[32];

    floatx4 acc[9][2];
    #pragma unroll
    for (int dy = 0; dy < 9; ++dy) {
        acc[dy][0] = floatx4{0.f, 0.f, 0.f, 0.f};
        acc[dy][1] = floatx4{0.f, 0.f, 0.f, 0.f};
    }

    {
        const float* p1 = o_base;
        #pragma unroll
        for (int i = 0; i < 8; ++i) ro[i] = p1[(size_t)i * HWp];
        if (t_valid) {
            const float* p2 = t_base;
            #pragma unroll
            for (int i = 0; i < 32; ++i) rt[i] = p2[(size_t)i * HWp];
        } else {
            #pragma unroll
            for (int i = 0; i < 32; ++i) rt[i] = 0.f;
        }
    }

    #pragma unroll
    for (int ck = 0; ck < 4; ++ck) {
        const int bf = ck & 1;
        {
            uint4 v;
            v.x = pk_bf16(ro[0], ro[1]);
            v.y = pk_bf16(ro[2], ro[3]);
            v.z = pk_bf16(ro[4], ro[5]);
            v.w = pk_bf16(ro[6], ro[7]);
            one_q[bf][o_rec] = v;
            #pragma unroll
            for (int kg = 0; kg < 4; ++kg) {
                uint4 u;
                u.x = pk_bf16(rt[kg * 8 + 0], rt[kg * 8 + 1]);
                u.y = pk_bf16(rt[kg * 8 + 2], rt[kg * 8 + 3]);
                u.z = pk_bf16(rt[kg * 8 + 4], rt[kg * 8 + 5]);
                u.w = pk_bf16(rt[kg * 8 + 6], rt[kg * 8 + 7]);
                two_q[bf][t_rec + kg * 16] = u;
            }
        }
        __syncthreads();

        if (ck < 3) {
            const float* p1 = o_base + (size_t)((ck + 1) * 32) * HWp;
            #pragma unroll
            for (int i = 0; i < 8; ++i) ro[i] = p1[(size_t)i * HWp];
            if (t_valid) {
                const float* p2 = t_base + (size_t)((ck + 1) * 32) * HWp;
                #pragma unroll
                for (int i = 0; i < 32; ++i) rt[i] = p2[(size_t)i * HWp];
            }
        }

        const short8 A = *reinterpret_cast<const short8*>(&one_q[bf][w * 64 + lane]);
        #pragma unroll
        for (int dy = 0; dy < 9; ++dy) {
            const int ry = w + dy;
            const short8 Bt0 = *reinterpret_cast<const short8*>(&two_q[bf][ry * 128 + lane]);
            const short8 Bt1 = *reinterpret_cast<const short8*>(&two_q[bf][ry * 128 + 64 + lane]);
            acc[dy][0] = __builtin_amdgcn_mfma_f32_16x16x32_bf16(A, Bt0, acc[dy][0], 0, 0, 0);
            acc[dy][1] = __builtin_amdgcn_mfma_f32_16x16x32_bf16(A, Bt1, acc[dy][1], 0, 0, 0);
        }
    }

    const int  qq = lane >> 4;
    const int  nn2 = lane & 15;
    const int  y  = y0 + w;
    const float scale = 1.0f / (float)C_;
    #pragma unroll
    for (int dy = 0; dy < 9; ++dy) {
        #pragma unroll
        for (int ct = 0; ct < 2; ++ct) {
            floatx4 v = acc[dy][ct];
            #pragma unroll
            for (int r = 0; r < 4; ++r) {
                int m  = qq * 4 + r;
                int dx = nn2 - m + ct * 16;
                if ((unsigned)dx <= 8u) {
                    size_t o = ((size_t)(b * 81 + dy * 9 + dx) * H_ + y) * W_ + (x0 + m);
                    out[o] = v[r] * scale;
                }
            }
        }
    }
}

extern "C" void kernel_launch(void* const* d_in, const int* in_sizes, int n_in,
                              void* d_out, int out_size, void* d_ws, size_t ws_size,
                              hipStream_t stream) {
    const float* one = (const float*)d_in[0];
    const float* two = (const float*)d_in[1];
    float* out = (float*)d_out;
    const size_t words = (size_t)B_ * 64 * HWp;        // pair-words per tensor
    const size_t need  = 2 * words * 4;                // 62,914,560 B
    if (d_ws != nullptr && ws_size >= need) {
        unsigned* two_p = (unsigned*)d_ws;
        unsigned* one_p = two_p + words;
        // prep: 1024 two-blocks + 1024 one-blocks, 384 threads x 5 units, deep ILP
        prep_convert<<<dim3(2048), dim3(384), 0, stream>>>(two, one, two_p, one_p);
        // corr3: 8 batches * 12 y-tiles * 10 x-tiles = 960 blocks
        corr3_kernel<<<dim3(960), dim3(512), 0, stream>>>(one_p, two_p, out);
    } else {
        corr_kernel<<<dim3(960), dim3(512), 0, stream>>>(one, two, out);
    }
}